// Round 6
// baseline (4283.942 us; speedup 1.0000x reference)
//
#include <hip/hip_runtime.h>

#define BATCH 1024
#define CDIM  512
#define DDIM  256
#define KCB   8192
#define HD    512
#define G3    1536
#define TSTEPS 8

// ---------------- workspace layout (float offsets) ----------------
#define WS_CB    ((size_t)0)          // [K,D]
#define WS_EW    ((size_t)2097152)    // [K,D]
#define WS_DW    ((size_t)4194304)    // [K,D]
#define WS_SM    ((size_t)6291456)    // [B,C]
#define WS_H     ((size_t)6815744)    // [B,HD]
#define WS_PREV  ((size_t)7340032)    // [B,D]
#define WS_Z     ((size_t)7602176)    // [B,D]
#define WS_GX    ((size_t)7864320)    // [B,3HD]
#define WS_GH    ((size_t)9437184)    // [B,3HD]
#define WS_GB    ((size_t)11010048)   // [B,1024]
#define WS_PIN   ((size_t)12058624)   // [B,1024]
#define WS_H1    ((size_t)13107200)   // [B,HD]
#define WS_CS    ((size_t)13631488)   // [K]
#define WS_CBSQ  ((size_t)13639680)   // [K]
#define WS_SZZ   ((size_t)13647872)   // [B]
#define WS_CNT   ((size_t)13648896)   // [K]
#define WS_NT    ((size_t)13657088)   // [1]+pad
#define WS_LOSS  ((size_t)13657090)   // [1]+pad
#define WS_IDX   ((size_t)13657092)   // [B] ints
#define WS_ROWK  ((size_t)13658116)   // [B] u64 (2048 floats, 8B-aligned)
#define WS_WGWB  ((size_t)13660164)   // [1024,512]
#define WS_BGBB  ((size_t)14184452)   // [1024]

// ---------------- output layout (f32 elements) ----------------
#define OUT_HF    ((size_t)0)
#define OUT_CODES ((size_t)524288)
#define OUT_IDX   ((size_t)2621440)
#define OUT_ZC    ((size_t)2629632)
#define OUT_LOSS  ((size_t)4726784)

// order-preserving map of f32 bits; col in low 32 bits -> ties pick lowest col
static __device__ __forceinline__ unsigned long long key32(float s, int col) {
  unsigned int u = __float_as_uint(s);
  u = (u & 0x80000000u) ? ~u : (u | 0x80000000u);
  return (((unsigned long long)u) << 32) | (unsigned long long)(unsigned int)col;
}

// numpy pairwise_sum for n=128 block: 8 accumulators, tree combine
static __device__ __forceinline__ float pw128(const float* a) {
  float r0=a[0],r1=a[1],r2=a[2],r3=a[3],r4=a[4],r5=a[5],r6=a[6],r7=a[7];
  for (int i = 8; i < 128; i += 8) {
    r0+=a[i+0]; r1+=a[i+1]; r2+=a[i+2]; r3+=a[i+3];
    r4+=a[i+4]; r5+=a[i+5]; r6+=a[i+6]; r7+=a[i+7];
  }
  return ((r0+r1)+(r2+r3))+((r4+r5)+(r6+r7));
}
// numpy pairwise for n=256: split 128+128
static __device__ __forceinline__ float pw256sq(const float* a, bool square) {
#pragma clang fp contract(off)
  float buf[128];
  if (square) { for (int i=0;i<128;++i){float v=a[i];buf[i]=v*v;} }
  else        { for (int i=0;i<128;++i) buf[i]=a[i]; }
  float s0 = pw128(buf);
  if (square) { for (int i=0;i<128;++i){float v=a[128+i];buf[i]=v*v;} }
  else        { for (int i=0;i<128;++i) buf[i]=a[128+i]; }
  float s1 = pw128(buf);
  return s0 + s1;
}

// ---------------- f32 GEMM, k-ascending single-accumulator FMA chain --------
// C[M,N] = act(A[M,K] * B[N,K]^T + bias[N]); BM=BN=64, BK=16, 256 thr
template<bool RELU>
__global__ __launch_bounds__(256) void gemm_nt(
    const float* __restrict__ A, int lda,
    const float* __restrict__ B, int ldb,
    float* __restrict__ C, int ldc,
    const float* __restrict__ bias, int K)
{
  __shared__ float As[16][68];
  __shared__ float Bs[16][68];
  const int tid = threadIdx.x;
  const int tx = tid & 15, ty = tid >> 4;
  const int m0 = blockIdx.x * 64, n0 = blockIdx.y * 64;
  const int lr = tid >> 2, lq = tid & 3;
  const float4* Ab = (const float4*)(A + (size_t)(m0 + lr) * lda);
  const float4* Bb = (const float4*)(B + (size_t)(n0 + lr) * ldb);
  float acc[4][4] = {};
  for (int k0 = 0; k0 < K; k0 += 16) {
    float4 av = Ab[(k0 >> 2) + lq];
    float4 bv = Bb[(k0 >> 2) + lq];
    __syncthreads();
    As[lq*4+0][lr] = av.x; As[lq*4+1][lr] = av.y;
    As[lq*4+2][lr] = av.z; As[lq*4+3][lr] = av.w;
    Bs[lq*4+0][lr] = bv.x; Bs[lq*4+1][lr] = bv.y;
    Bs[lq*4+2][lr] = bv.z; Bs[lq*4+3][lr] = bv.w;
    __syncthreads();
#pragma unroll
    for (int kk = 0; kk < 16; ++kk) {
      float4 a = *(const float4*)&As[kk][ty*4];
      float4 b = *(const float4*)&Bs[kk][tx*4];
      acc[0][0]=fmaf(a.x,b.x,acc[0][0]); acc[0][1]=fmaf(a.x,b.y,acc[0][1]); acc[0][2]=fmaf(a.x,b.z,acc[0][2]); acc[0][3]=fmaf(a.x,b.w,acc[0][3]);
      acc[1][0]=fmaf(a.y,b.x,acc[1][0]); acc[1][1]=fmaf(a.y,b.y,acc[1][1]); acc[1][2]=fmaf(a.y,b.z,acc[1][2]); acc[1][3]=fmaf(a.y,b.w,acc[1][3]);
      acc[2][0]=fmaf(a.z,b.x,acc[2][0]); acc[2][1]=fmaf(a.z,b.y,acc[2][1]); acc[2][2]=fmaf(a.z,b.z,acc[2][2]); acc[2][3]=fmaf(a.z,b.w,acc[2][3]);
      acc[3][0]=fmaf(a.w,b.x,acc[3][0]); acc[3][1]=fmaf(a.w,b.y,acc[3][1]); acc[3][2]=fmaf(a.w,b.z,acc[3][2]); acc[3][3]=fmaf(a.w,b.w,acc[3][3]);
    }
  }
  {
#pragma clang fp contract(off)
#pragma unroll
    for (int i = 0; i < 4; ++i) {
#pragma unroll
      for (int j = 0; j < 4; ++j) {
        float v = acc[i][j] + bias[n0 + tx*4 + j];   // bias added AFTER gemm (np order)
        if (RELU) v = fmaxf(v, 0.0f);
        C[(size_t)(m0 + ty*4 + i) * ldc + n0 + tx*4 + j] = v;
      }
    }
  }
}

// --------- VQ: G = z.cb_k (sgemm-order chain); d = (szz - 2G) + scb; argmin --
__global__ __launch_bounds__(256) void gemm_score_argmin(
    const float* __restrict__ A,      // z [B,D]
    const float* __restrict__ Bc,     // cb [K,D]
    const float* __restrict__ cbsq,   // [K]  np-pairwise f32
    const float* __restrict__ szz,    // [B]  np-pairwise f32
    unsigned long long* __restrict__ rowkeys)
{
  __shared__ float As[16][68];
  __shared__ float Bs[16][68];
  __shared__ unsigned long long Ks[64][17];
  const int tid = threadIdx.x;
  const int tx = tid & 15, ty = tid >> 4;
  const int m0 = blockIdx.x * 64, n0 = blockIdx.y * 64;
  const int lr = tid >> 2, lq = tid & 3;
  const float4* Ab = (const float4*)(A + (size_t)(m0 + lr) * DDIM);
  const float4* Bb = (const float4*)(Bc + (size_t)(n0 + lr) * DDIM);
  float acc[4][4] = {};
  for (int k0 = 0; k0 < DDIM; k0 += 16) {
    float4 av = Ab[(k0 >> 2) + lq];
    float4 bv = Bb[(k0 >> 2) + lq];
    __syncthreads();
    As[lq*4+0][lr] = av.x; As[lq*4+1][lr] = av.y;
    As[lq*4+2][lr] = av.z; As[lq*4+3][lr] = av.w;
    Bs[lq*4+0][lr] = bv.x; Bs[lq*4+1][lr] = bv.y;
    Bs[lq*4+2][lr] = bv.z; Bs[lq*4+3][lr] = bv.w;
    __syncthreads();
#pragma unroll
    for (int kk = 0; kk < 16; ++kk) {
      float4 a = *(const float4*)&As[kk][ty*4];
      float4 b = *(const float4*)&Bs[kk][tx*4];
      acc[0][0]=fmaf(a.x,b.x,acc[0][0]); acc[0][1]=fmaf(a.x,b.y,acc[0][1]); acc[0][2]=fmaf(a.x,b.z,acc[0][2]); acc[0][3]=fmaf(a.x,b.w,acc[0][3]);
      acc[1][0]=fmaf(a.y,b.x,acc[1][0]); acc[1][1]=fmaf(a.y,b.y,acc[1][1]); acc[1][2]=fmaf(a.y,b.z,acc[1][2]); acc[1][3]=fmaf(a.y,b.w,acc[1][3]);
      acc[2][0]=fmaf(a.z,b.x,acc[2][0]); acc[2][1]=fmaf(a.z,b.y,acc[2][1]); acc[2][2]=fmaf(a.z,b.z,acc[2][2]); acc[2][3]=fmaf(a.z,b.w,acc[2][3]);
      acc[3][0]=fmaf(a.w,b.x,acc[3][0]); acc[3][1]=fmaf(a.w,b.y,acc[3][1]); acc[3][2]=fmaf(a.w,b.z,acc[3][2]); acc[3][3]=fmaf(a.w,b.w,acc[3][3]);
    }
  }
  {
#pragma clang fp contract(off)
    const int nb = n0 + tx * 4;
#pragma unroll
    for (int i = 0; i < 4; ++i) {
      float sz = szz[m0 + ty*4 + i];
      unsigned long long kb[4];
#pragma unroll
      for (int j = 0; j < 4; ++j) {
        float g2 = 2.0f * acc[i][j];     // exact (pow2 scale)
        float t1 = sz - g2;              // np: (szz - 2G)
        float d  = t1 + cbsq[nb + j];    // np: ... + scb
        kb[j] = key32(d, nb + j);
      }
      unsigned long long ka = kb[0] < kb[1] ? kb[0] : kb[1];
      unsigned long long kc = kb[2] < kb[3] ? kb[2] : kb[3];
      Ks[ty*4 + i][tx] = ka < kc ? ka : kc;
    }
  }
  __syncthreads();
  if (tid < 64) {
    unsigned long long best = Ks[tid][0];
#pragma unroll
    for (int t = 1; t < 16; ++t) {
      unsigned long long v = Ks[tid][t];
      best = v < best ? v : best;
    }
    atomicMin(&rowkeys[m0 + tid], best);
  }
}

// ---------------- elementwise / reduction kernels (np-f32 faithful) ---------
__global__ __launch_bounds__(256) void pw256_rows_kernel(const float* __restrict__ src,
                                                         float* __restrict__ dst,
                                                         int square) {
  int r = blockIdx.x * 256 + threadIdx.x;
  dst[r] = pw256sq(src + (size_t)r * 256, square != 0);
}

__global__ __launch_bounds__(256) void smean_kernel(const float* __restrict__ sf,
                                                    float* __restrict__ sm) {
#pragma clang fp contract(off)
  int i = blockIdx.x * 256 + threadIdx.x;     // B*C threads
  const float* a = sf + (size_t)i * 49;
  // numpy pairwise n=49: 8 accs over 48, combine, + a[48]
  float r0=a[0],r1=a[1],r2=a[2],r3=a[3],r4=a[4],r5=a[5],r6=a[6],r7=a[7];
  for (int k = 8; k < 48; k += 8) {
    r0+=a[k+0]; r1+=a[k+1]; r2+=a[k+2]; r3+=a[k+3];
    r4+=a[k+4]; r5+=a[k+5]; r6+=a[k+6]; r7+=a[k+7];
  }
  float res = ((r0+r1)+(r2+r3))+((r4+r5)+(r6+r7));
  res += a[48];
  sm[i] = res / 49.0f;
}

__global__ __launch_bounds__(256) void previnit_kernel(const float* __restrict__ bos,
                                                       float* __restrict__ prev) {
  int i = blockIdx.x * 256 + threadIdx.x;
  prev[i] = bos[i & (DDIM - 1)];
}

__global__ __launch_bounds__(256) void gru_kernel(const float* __restrict__ gx,
                                                  const float* __restrict__ gh,
                                                  float* __restrict__ h) {
#pragma clang fp contract(off)
  int i = blockIdx.x * 256 + threadIdx.x;
  int b = i >> 9, j = i & 511;
  size_t o = (size_t)b * G3;
  float xr = gx[o + j], xz = gx[o + 512 + j], xn = gx[o + 1024 + j];
  float hr = gh[o + j], hz = gh[o + 512 + j], hn = gh[o + 1024 + j];
  float ar = xr + hr;
  float az = xz + hz;
  float er = expf(-ar);
  float ez = expf(-az);
  float r  = 1.0f / (1.0f + er);
  float zz = 1.0f / (1.0f + ez);
  float rh = r * hn;
  float an = xn + rh;
  float n  = tanhf(an);
  float hold = h[i];
  float t1 = (1.0f - zz) * n;
  float t2 = zz * hold;
  h[i] = t1 + t2;
}

__global__ __launch_bounds__(256) void film_kernel(const float* __restrict__ gb,
                                                   const float* __restrict__ sm,
                                                   const float* __restrict__ h,
                                                   float* __restrict__ pin) {
#pragma clang fp contract(off)
  int i = blockIdx.x * 256 + threadIdx.x;
  int b = i >> 9, j = i & 511;
  float gamma = gb[(size_t)b * 1024 + j];
  float beta  = gb[(size_t)b * 1024 + 512 + j];
  float t1 = 1.0f + gamma;
  float t2 = t1 * sm[i];
  float cval = t2 + beta;
  pin[(size_t)b * 1024 + j] = h[i];
  pin[(size_t)b * 1024 + 512 + j] = cval;
}

__global__ __launch_bounds__(256) void vq_apply_kernel(
    const unsigned long long* __restrict__ rowkeys,
    const float* __restrict__ cb, const float* __restrict__ zbuf,
    float* __restrict__ prev, int* __restrict__ idxarr, float* __restrict__ counts,
    float* __restrict__ loss_acc, float* __restrict__ out, int t)
{
#pragma clang fp contract(off)
  int b = blockIdx.x, d = threadIdx.x;
  int idx = (int)(rowkeys[b] & 0xFFFFFFFFull);
  float zq = cb[(size_t)idx * DDIM + d];
  float zb = zbuf[(size_t)b * DDIM + d];
  float delta = zq - zb;
  float zste = zb + delta;                  // z + (z_q - z)
  size_t td = ((size_t)b * TSTEPS + t) * DDIM + d;
  out[OUT_CODES + td] = zste;
  out[OUT_ZC + td] = zb;
  prev[(size_t)b * DDIM + d] = zste;
  if (d == 0) {
    idxarr[b] = idx;
    out[OUT_IDX + (size_t)b * TSTEPS + t] = (float)idx;
    atomicAdd(&counts[idx], 1.0f);
  }
  float diff = zb - zq;
  __shared__ float red[256];
  red[d] = diff * diff; __syncthreads();
  for (int s = 128; s > 0; s >>= 1) { if (d < s) red[d] += red[d + s]; __syncthreads(); }
  if (d == 0) atomicAdd(loss_acc, red[0]);
}

// np.add.at order: accumulate z_b into dw[k] in ascending-b order (deterministic)
__global__ __launch_bounds__(256) void dw_build_kernel(const int* __restrict__ idxarr,
                                                       const float* __restrict__ zbuf,
                                                       float* __restrict__ dw) {
#pragma clang fp contract(off)
  __shared__ int sidx[BATCH];
  int k = blockIdx.x, d = threadIdx.x;
  for (int b = d; b < BATCH; b += 256) sidx[b] = idxarr[b];
  __syncthreads();
  float acc = 0.0f;
  for (int b = 0; b < BATCH; ++b) {
    if (sidx[b] == k) acc += zbuf[(size_t)b * DDIM + d];   // block-uniform branch
  }
  dw[(size_t)k * DDIM + d] = acc;
}

__global__ __launch_bounds__(256) void cs_update_kernel(float* __restrict__ cs,
                                                        const float* __restrict__ counts) {
#pragma clang fp contract(off)
  int k = blockIdx.x * 256 + threadIdx.x;
  float a = 0.99f * cs[k];
  float b = 0.01f * counts[k];
  cs[k] = a + b;
}

// n_tot = np pairwise sum over 8192 = perfect tree over 64 pw128 leaves
__global__ __launch_bounds__(256) void ntot_kernel(const float* __restrict__ cs,
                                                   float* __restrict__ nt) {
#pragma clang fp contract(off)
  __shared__ float s[64];
  int j = threadIdx.x;
  if (j < 64) s[j] = pw128(cs + j * 128);
  __syncthreads();
  if (j == 0) {
    float v[64];
    for (int i = 0; i < 64; ++i) v[i] = s[i];
    for (int len = 64; len > 1; len >>= 1)
      for (int i = 0; i < (len >> 1); ++i) v[i] = v[2*i] + v[2*i+1];
    nt[0] = v[0];
  }
}

__global__ __launch_bounds__(256) void cs_smooth_kernel(float* __restrict__ cs,
                                                        const float* __restrict__ nt) {
#pragma clang fp contract(off)
  int k = blockIdx.x * 256 + threadIdx.x;
  float n = nt[0];
  float t1 = cs[k] + 1e-5f;
  float den = n + 0.08192f;          // f32(K*EPS)
  float q = t1 / den;
  cs[k] = q * n;
}

__global__ __launch_bounds__(256) void ema_update_kernel(
    float* __restrict__ ew, const float* __restrict__ dw,
    const float* __restrict__ cs, float* __restrict__ cb)
{
#pragma clang fp contract(off)
  int i = blockIdx.x * 256 + threadIdx.x;   // K*D threads
  int k = i >> 8;
  float a = 0.99f * ew[i];
  float b = 0.01f * dw[i];
  float e = a + b;
  ew[i] = e;
  cb[i] = e / cs[k];
}

__global__ __launch_bounds__(256) void hfinal_kernel(const float* __restrict__ h,
                                                     float* __restrict__ out) {
  int i = blockIdx.x * 256 + threadIdx.x;
  out[OUT_HF + i] = h[i];
}

__global__ void loss_kernel(const float* __restrict__ loss_acc,
                            float* __restrict__ out) {
  out[OUT_LOSS] = 0.25f * (*loss_acc) / ((float)(BATCH * DDIM)) / (float)TSTEPS;
}

// ---------------- launch ----------------
extern "C" void kernel_launch(void* const* d_in, const int* in_sizes, int n_in,
                              void* d_out, int out_size, void* d_ws, size_t ws_size,
                              hipStream_t stream) {
  const float* sf    = (const float*)d_in[0];
  const float* bos   = (const float*)d_in[1];
  const float* W_ih  = (const float*)d_in[2];
  const float* W_hh  = (const float*)d_in[3];
  const float* b_ih  = (const float*)d_in[4];
  const float* b_hh  = (const float*)d_in[5];
  const float* Wg    = (const float*)d_in[6];
  const float* bg    = (const float*)d_in[7];
  const float* Wb    = (const float*)d_in[8];
  const float* bb    = (const float*)d_in[9];
  const float* W1    = (const float*)d_in[10];
  const float* b1    = (const float*)d_in[11];
  const float* W2    = (const float*)d_in[12];
  const float* b2    = (const float*)d_in[13];
  const float* cb_in = (const float*)d_in[14];
  const float* cs_in = (const float*)d_in[15];
  const float* ew_in = (const float*)d_in[16];

  float* ws  = (float*)d_ws;
  float* out = (float*)d_out;

  float* CB   = ws + WS_CB;
  float* EW   = ws + WS_EW;
  float* DW   = ws + WS_DW;
  float* SM   = ws + WS_SM;
  float* H    = ws + WS_H;
  float* PREV = ws + WS_PREV;
  float* Z    = ws + WS_Z;
  float* GX   = ws + WS_GX;
  float* GH   = ws + WS_GH;
  float* GB   = ws + WS_GB;
  float* PIN  = ws + WS_PIN;
  float* H1   = ws + WS_H1;
  float* CS   = ws + WS_CS;
  float* CBSQ = ws + WS_CBSQ;
  float* SZZ  = ws + WS_SZZ;
  float* CNT  = ws + WS_CNT;
  float* NT   = ws + WS_NT;
  float* LOSS = ws + WS_LOSS;
  int*   IDX  = (int*)(ws + WS_IDX);
  unsigned long long* ROWK = (unsigned long long*)(ws + WS_ROWK);
  float* WGWB = ws + WS_WGWB;
  float* BGBB = ws + WS_BGBB;

  // ---- per-launch init ----
  (void)hipMemcpyAsync(CB, cb_in, (size_t)KCB * DDIM * 4, hipMemcpyDeviceToDevice, stream);
  (void)hipMemcpyAsync(EW, ew_in, (size_t)KCB * DDIM * 4, hipMemcpyDeviceToDevice, stream);
  (void)hipMemcpyAsync(CS, cs_in, (size_t)KCB * 4, hipMemcpyDeviceToDevice, stream);
  (void)hipMemcpyAsync(WGWB, Wg, (size_t)CDIM * HD * 4, hipMemcpyDeviceToDevice, stream);
  (void)hipMemcpyAsync(WGWB + (size_t)CDIM * HD, Wb, (size_t)CDIM * HD * 4, hipMemcpyDeviceToDevice, stream);
  (void)hipMemcpyAsync(BGBB, bg, CDIM * 4, hipMemcpyDeviceToDevice, stream);
  (void)hipMemcpyAsync(BGBB + CDIM, bb, CDIM * 4, hipMemcpyDeviceToDevice, stream);
  (void)hipMemsetAsync(H, 0, (size_t)BATCH * HD * 4, stream);
  (void)hipMemsetAsync(LOSS, 0, 8, stream);
  previnit_kernel<<<BATCH * DDIM / 256, 256, 0, stream>>>(bos, PREV);
  smean_kernel<<<BATCH * CDIM / 256, 256, 0, stream>>>(sf, SM);
  pw256_rows_kernel<<<KCB / 256, 256, 0, stream>>>(CB, CBSQ, 1);

  for (int t = 0; t < TSTEPS; ++t) {
    (void)hipMemsetAsync(CNT, 0, (size_t)KCB * 4, stream);
    (void)hipMemsetAsync(ROWK, 0xFF, BATCH * 8, stream);

    // GRU gates
    gemm_nt<false><<<dim3(16, G3/64), 256, 0, stream>>>(PREV, DDIM, W_ih, DDIM, GX, G3, b_ih, DDIM);
    gemm_nt<false><<<dim3(16, G3/64), 256, 0, stream>>>(H, HD, W_hh, HD, GH, G3, b_hh, HD);
    gru_kernel<<<BATCH * HD / 256, 256, 0, stream>>>(GX, GH, H);

    // FiLM + pin
    gemm_nt<false><<<dim3(16, 1024/64), 256, 0, stream>>>(H, HD, WGWB, HD, GB, 1024, BGBB, HD);
    film_kernel<<<BATCH * CDIM / 256, 256, 0, stream>>>(GB, SM, H, PIN);

    // MLP
    gemm_nt<true ><<<dim3(16, HD/64), 256, 0, stream>>>(PIN, 1024, W1, 1024, H1, HD, b1, 1024);
    gemm_nt<false><<<dim3(16, DDIM/64), 256, 0, stream>>>(H1, HD, W2, HD, Z, DDIM, b2, HD);

    // VQ
    pw256_rows_kernel<<<BATCH / 256, 256, 0, stream>>>(Z, SZZ, 1);
    gemm_score_argmin<<<dim3(16, KCB/64), 256, 0, stream>>>(Z, CB, CBSQ, SZZ, ROWK);
    vq_apply_kernel<<<BATCH, 256, 0, stream>>>(ROWK, CB, Z, PREV, IDX, CNT, LOSS, out, t);

    // EMA (np order, deterministic scatter)
    dw_build_kernel<<<KCB, 256, 0, stream>>>(IDX, Z, DW);
    cs_update_kernel<<<KCB/256, 256, 0, stream>>>(CS, CNT);
    ntot_kernel<<<1, 256, 0, stream>>>(CS, NT);
    cs_smooth_kernel<<<KCB/256, 256, 0, stream>>>(CS, NT);
    ema_update_kernel<<<KCB * DDIM / 256, 256, 0, stream>>>(EW, DW, CS, CB);
    pw256_rows_kernel<<<KCB / 256, 256, 0, stream>>>(CB, CBSQ, 1);
  }

  hfinal_kernel<<<BATCH * HD / 256, 256, 0, stream>>>(H, out);
  loss_kernel<<<1, 1, 0, stream>>>(LOSS, out);
}

// Round 7
// 2905.622 us; speedup vs baseline: 1.4744x; 1.4744x over previous
//
#include <hip/hip_runtime.h>

#define BATCH 1024
#define CDIM  512
#define DDIM  256
#define KCB   8192
#define HD    512
#define G3    1536
#define TSTEPS 8

// ---------------- workspace layout (float offsets) ----------------
#define WS_CB    ((size_t)0)          // [K,D]
#define WS_EW    ((size_t)2097152)    // [K,D]
#define WS_CSR   ((size_t)4194304)    // ints: list[1024] | base[8192] | cnts[8192]
#define WS_SM    ((size_t)6291456)    // [B,C]
#define WS_H     ((size_t)6815744)    // [B,HD]
#define WS_PREV  ((size_t)7340032)    // [B,D]
#define WS_Z     ((size_t)7602176)    // [B,D]
#define WS_GX    ((size_t)7864320)    // [B,3HD]
#define WS_GH    ((size_t)9437184)    // [B,3HD]
#define WS_GB    ((size_t)11010048)   // [B,1024]
#define WS_PIN   ((size_t)12058624)   // [B,1024]
#define WS_H1    ((size_t)13107200)   // [B,HD]
#define WS_CS    ((size_t)13631488)   // [K]
#define WS_CBSQ  ((size_t)13639680)   // [K]
#define WS_SZZ   ((size_t)13647872)   // [B]
#define WS_NT    ((size_t)13657088)   // [1]+pad
#define WS_LOSS  ((size_t)13657090)   // [1]+pad
#define WS_IDX   ((size_t)13657092)   // [B] ints
#define WS_ROWK  ((size_t)13658116)   // [B] u64 (8B-aligned)
#define WS_WGWB  ((size_t)13660164)   // [1024,512]
#define WS_BGBB  ((size_t)14184452)   // [1024]

// ---------------- output layout (f32 elements) ----------------
#define OUT_HF    ((size_t)0)
#define OUT_CODES ((size_t)524288)
#define OUT_IDX   ((size_t)2621440)
#define OUT_ZC    ((size_t)2629632)
#define OUT_LOSS  ((size_t)4726784)

// order-preserving map of f32 bits; col in low 32 bits -> ties pick lowest col
static __device__ __forceinline__ unsigned long long key32(float s, int col) {
  unsigned int u = __float_as_uint(s);
  u = (u & 0x80000000u) ? ~u : (u | 0x80000000u);
  return (((unsigned long long)u) << 32) | (unsigned long long)(unsigned int)col;
}

// numpy pairwise_sum for n=128 block: 8 accumulators, tree combine
static __device__ __forceinline__ float pw128(const float* a) {
  float r0=a[0],r1=a[1],r2=a[2],r3=a[3],r4=a[4],r5=a[5],r6=a[6],r7=a[7];
  for (int i = 8; i < 128; i += 8) {
    r0+=a[i+0]; r1+=a[i+1]; r2+=a[i+2]; r3+=a[i+3];
    r4+=a[i+4]; r5+=a[i+5]; r6+=a[i+6]; r7+=a[i+7];
  }
  return ((r0+r1)+(r2+r3))+((r4+r5)+(r6+r7));
}
// numpy pairwise for n=256: split 128+128 (optionally square elements)
static __device__ __forceinline__ float pw256sq(const float* a, bool square) {
#pragma clang fp contract(off)
  float buf[128];
  if (square) { for (int i=0;i<128;++i){float v=a[i];buf[i]=v*v;} }
  else        { for (int i=0;i<128;++i) buf[i]=a[i]; }
  float s0 = pw128(buf);
  if (square) { for (int i=0;i<128;++i){float v=a[128+i];buf[i]=v*v;} }
  else        { for (int i=0;i<128;++i) buf[i]=a[128+i]; }
  float s1 = pw128(buf);
  return s0 + s1;
}

// ---------------- f32 GEMM, k-ascending single-accumulator FMA chain --------
// C[M,N] = act(A[M,K] * B[N,K]^T + bias[N]); BM=BN=64, BK=16, 256 thr
template<bool RELU>
__global__ __launch_bounds__(256) void gemm_nt(
    const float* __restrict__ A, int lda,
    const float* __restrict__ B, int ldb,
    float* __restrict__ C, int ldc,
    const float* __restrict__ bias, int K)
{
  __shared__ float As[16][68];
  __shared__ float Bs[16][68];
  const int tid = threadIdx.x;
  const int tx = tid & 15, ty = tid >> 4;
  const int m0 = blockIdx.x * 64, n0 = blockIdx.y * 64;
  const int lr = tid >> 2, lq = tid & 3;
  const float4* Ab = (const float4*)(A + (size_t)(m0 + lr) * lda);
  const float4* Bb = (const float4*)(B + (size_t)(n0 + lr) * ldb);
  float acc[4][4] = {};
  for (int k0 = 0; k0 < K; k0 += 16) {
    float4 av = Ab[(k0 >> 2) + lq];
    float4 bv = Bb[(k0 >> 2) + lq];
    __syncthreads();
    As[lq*4+0][lr] = av.x; As[lq*4+1][lr] = av.y;
    As[lq*4+2][lr] = av.z; As[lq*4+3][lr] = av.w;
    Bs[lq*4+0][lr] = bv.x; Bs[lq*4+1][lr] = bv.y;
    Bs[lq*4+2][lr] = bv.z; Bs[lq*4+3][lr] = bv.w;
    __syncthreads();
#pragma unroll
    for (int kk = 0; kk < 16; ++kk) {
      float4 a = *(const float4*)&As[kk][ty*4];
      float4 b = *(const float4*)&Bs[kk][tx*4];
      acc[0][0]=fmaf(a.x,b.x,acc[0][0]); acc[0][1]=fmaf(a.x,b.y,acc[0][1]); acc[0][2]=fmaf(a.x,b.z,acc[0][2]); acc[0][3]=fmaf(a.x,b.w,acc[0][3]);
      acc[1][0]=fmaf(a.y,b.x,acc[1][0]); acc[1][1]=fmaf(a.y,b.y,acc[1][1]); acc[1][2]=fmaf(a.y,b.z,acc[1][2]); acc[1][3]=fmaf(a.y,b.w,acc[1][3]);
      acc[2][0]=fmaf(a.z,b.x,acc[2][0]); acc[2][1]=fmaf(a.z,b.y,acc[2][1]); acc[2][2]=fmaf(a.z,b.z,acc[2][2]); acc[2][3]=fmaf(a.z,b.w,acc[2][3]);
      acc[3][0]=fmaf(a.w,b.x,acc[3][0]); acc[3][1]=fmaf(a.w,b.y,acc[3][1]); acc[3][2]=fmaf(a.w,b.z,acc[3][2]); acc[3][3]=fmaf(a.w,b.w,acc[3][3]);
    }
  }
  {
#pragma clang fp contract(off)
#pragma unroll
    for (int i = 0; i < 4; ++i) {
#pragma unroll
      for (int j = 0; j < 4; ++j) {
        float v = acc[i][j] + bias[n0 + tx*4 + j];   // bias added AFTER gemm (np order)
        if (RELU) v = fmaxf(v, 0.0f);
        C[(size_t)(m0 + ty*4 + i) * ldc + n0 + tx*4 + j] = v;
      }
    }
  }
}

// --------- VQ: G = z.cb_k (sgemm-order chain); d = (szz - 2G) + scb; argmin --
__global__ __launch_bounds__(256) void gemm_score_argmin(
    const float* __restrict__ A,      // z [B,D]
    const float* __restrict__ Bc,     // cb [K,D]
    const float* __restrict__ cbsq,   // [K]  np-pairwise f32
    const float* __restrict__ szz,    // [B]  np-pairwise f32
    unsigned long long* __restrict__ rowkeys)
{
  __shared__ float As[16][68];
  __shared__ float Bs[16][68];
  __shared__ unsigned long long Ks[64][17];
  const int tid = threadIdx.x;
  const int tx = tid & 15, ty = tid >> 4;
  const int m0 = blockIdx.x * 64, n0 = blockIdx.y * 64;
  const int lr = tid >> 2, lq = tid & 3;
  const float4* Ab = (const float4*)(A + (size_t)(m0 + lr) * DDIM);
  const float4* Bb = (const float4*)(Bc + (size_t)(n0 + lr) * DDIM);
  float acc[4][4] = {};
  for (int k0 = 0; k0 < DDIM; k0 += 16) {
    float4 av = Ab[(k0 >> 2) + lq];
    float4 bv = Bb[(k0 >> 2) + lq];
    __syncthreads();
    As[lq*4+0][lr] = av.x; As[lq*4+1][lr] = av.y;
    As[lq*4+2][lr] = av.z; As[lq*4+3][lr] = av.w;
    Bs[lq*4+0][lr] = bv.x; Bs[lq*4+1][lr] = bv.y;
    Bs[lq*4+2][lr] = bv.z; Bs[lq*4+3][lr] = bv.w;
    __syncthreads();
#pragma unroll
    for (int kk = 0; kk < 16; ++kk) {
      float4 a = *(const float4*)&As[kk][ty*4];
      float4 b = *(const float4*)&Bs[kk][tx*4];
      acc[0][0]=fmaf(a.x,b.x,acc[0][0]); acc[0][1]=fmaf(a.x,b.y,acc[0][1]); acc[0][2]=fmaf(a.x,b.z,acc[0][2]); acc[0][3]=fmaf(a.x,b.w,acc[0][3]);
      acc[1][0]=fmaf(a.y,b.x,acc[1][0]); acc[1][1]=fmaf(a.y,b.y,acc[1][1]); acc[1][2]=fmaf(a.y,b.z,acc[1][2]); acc[1][3]=fmaf(a.y,b.w,acc[1][3]);
      acc[2][0]=fmaf(a.z,b.x,acc[2][0]); acc[2][1]=fmaf(a.z,b.y,acc[2][1]); acc[2][2]=fmaf(a.z,b.z,acc[2][2]); acc[2][3]=fmaf(a.z,b.w,acc[2][3]);
      acc[3][0]=fmaf(a.w,b.x,acc[3][0]); acc[3][1]=fmaf(a.w,b.y,acc[3][1]); acc[3][2]=fmaf(a.w,b.z,acc[3][2]); acc[3][3]=fmaf(a.w,b.w,acc[3][3]);
    }
  }
  {
#pragma clang fp contract(off)
    const int nb = n0 + tx * 4;
#pragma unroll
    for (int i = 0; i < 4; ++i) {
      float sz = szz[m0 + ty*4 + i];
      unsigned long long kb[4];
#pragma unroll
      for (int j = 0; j < 4; ++j) {
        float g2 = 2.0f * acc[i][j];     // exact (pow2 scale)
        float t1 = sz - g2;              // np: (szz - 2G)
        float d  = t1 + cbsq[nb + j];    // np: ... + scb
        kb[j] = key32(d, nb + j);
      }
      unsigned long long ka = kb[0] < kb[1] ? kb[0] : kb[1];
      unsigned long long kc = kb[2] < kb[3] ? kb[2] : kb[3];
      Ks[ty*4 + i][tx] = ka < kc ? ka : kc;
    }
  }
  __syncthreads();
  if (tid < 64) {
    unsigned long long best = Ks[tid][0];
#pragma unroll
    for (int t = 1; t < 16; ++t) {
      unsigned long long v = Ks[tid][t];
      best = v < best ? v : best;
    }
    atomicMin(&rowkeys[m0 + tid], best);
  }
}

// ---------------- elementwise / reduction kernels (np-f32 faithful) ---------
__global__ __launch_bounds__(256) void pw256_rows_kernel(const float* __restrict__ src,
                                                         float* __restrict__ dst,
                                                         int square) {
  int r = blockIdx.x * 256 + threadIdx.x;
  dst[r] = pw256sq(src + (size_t)r * 256, square != 0);
}

__global__ __launch_bounds__(256) void smean_kernel(const float* __restrict__ sf,
                                                    float* __restrict__ sm) {
#pragma clang fp contract(off)
  int i = blockIdx.x * 256 + threadIdx.x;     // B*C threads
  const float* a = sf + (size_t)i * 49;
  float r0=a[0],r1=a[1],r2=a[2],r3=a[3],r4=a[4],r5=a[5],r6=a[6],r7=a[7];
  for (int k = 8; k < 48; k += 8) {
    r0+=a[k+0]; r1+=a[k+1]; r2+=a[k+2]; r3+=a[k+3];
    r4+=a[k+4]; r5+=a[k+5]; r6+=a[k+6]; r7+=a[k+7];
  }
  float res = ((r0+r1)+(r2+r3))+((r4+r5)+(r6+r7));
  res += a[48];
  sm[i] = res / 49.0f;
}

__global__ __launch_bounds__(256) void previnit_kernel(const float* __restrict__ bos,
                                                       float* __restrict__ prev) {
  int i = blockIdx.x * 256 + threadIdx.x;
  prev[i] = bos[i & (DDIM - 1)];
}

__global__ __launch_bounds__(256) void gru_kernel(const float* __restrict__ gx,
                                                  const float* __restrict__ gh,
                                                  float* __restrict__ h) {
#pragma clang fp contract(off)
  int i = blockIdx.x * 256 + threadIdx.x;
  int b = i >> 9, j = i & 511;
  size_t o = (size_t)b * G3;
  float xr = gx[o + j], xz = gx[o + 512 + j], xn = gx[o + 1024 + j];
  float hr = gh[o + j], hz = gh[o + 512 + j], hn = gh[o + 1024 + j];
  float ar = xr + hr;
  float az = xz + hz;
  float er = expf(-ar);
  float ez = expf(-az);
  float r  = 1.0f / (1.0f + er);
  float zz = 1.0f / (1.0f + ez);
  float rh = r * hn;
  float an = xn + rh;
  float n  = tanhf(an);
  float hold = h[i];
  float t1 = (1.0f - zz) * n;
  float t2 = zz * hold;
  h[i] = t1 + t2;
}

__global__ __launch_bounds__(256) void film_kernel(const float* __restrict__ gb,
                                                   const float* __restrict__ sm,
                                                   const float* __restrict__ h,
                                                   float* __restrict__ pin) {
#pragma clang fp contract(off)
  int i = blockIdx.x * 256 + threadIdx.x;
  int b = i >> 9, j = i & 511;
  float gamma = gb[(size_t)b * 1024 + j];
  float beta  = gb[(size_t)b * 1024 + 512 + j];
  float t1 = 1.0f + gamma;
  float t2 = t1 * sm[i];
  float cval = t2 + beta;
  pin[(size_t)b * 1024 + j] = h[i];
  pin[(size_t)b * 1024 + 512 + j] = cval;
}

__global__ __launch_bounds__(256) void vq_apply_kernel(
    const unsigned long long* __restrict__ rowkeys,
    const float* __restrict__ cb, const float* __restrict__ zbuf,
    float* __restrict__ prev, int* __restrict__ idxarr,
    float* __restrict__ loss_acc, float* __restrict__ out, int t)
{
#pragma clang fp contract(off)
  int b = blockIdx.x, d = threadIdx.x;
  int idx = (int)(rowkeys[b] & 0xFFFFFFFFull);
  float zq = cb[(size_t)idx * DDIM + d];
  float zb = zbuf[(size_t)b * DDIM + d];
  float delta = zq - zb;
  float zste = zb + delta;                  // z + (z_q - z)
  size_t td = ((size_t)b * TSTEPS + t) * DDIM + d;
  out[OUT_CODES + td] = zste;
  out[OUT_ZC + td] = zb;
  prev[(size_t)b * DDIM + d] = zste;
  if (d == 0) {
    idxarr[b] = idx;
    out[OUT_IDX + (size_t)b * TSTEPS + t] = (float)idx;
  }
  float diff = zb - zq;
  __shared__ float red[256];
  red[d] = diff * diff; __syncthreads();
  for (int s = 128; s > 0; s >>= 1) { if (d < s) red[d] += red[d + s]; __syncthreads(); }
  if (d == 0) atomicAdd(loss_acc, red[0]);
}

// ---- CSR bucket build: rank within equal idx (ascending b == np.add.at order)
__global__ __launch_bounds__(1024) void csr_build_kernel(const int* __restrict__ idxarr,
                                                         int* __restrict__ list,
                                                         int* __restrict__ base,
                                                         int* __restrict__ cnts) {
  __shared__ int sidx[BATCH];
  __shared__ int scnt[KCB];       // 32 KB
  __shared__ int spart[1024];
  const int t = threadIdx.x;
  sidx[t] = idxarr[t];
  for (int i = t; i < KCB; i += 1024) scnt[i] = 0;
  __syncthreads();
  const int my = sidx[t];
  atomicAdd(&scnt[my], 1);
  int rank = 0;
  for (int b = 0; b < t; ++b) rank += (sidx[b] == my) ? 1 : 0;
  __syncthreads();
  // exclusive scan of scnt: chunk-of-8 per thread, serial scan of 1024 partials
  const int c0 = t * 8;
  int loc[8]; int s0 = 0;
#pragma unroll
  for (int i = 0; i < 8; ++i) { loc[i] = s0; s0 += scnt[c0 + i]; }
  spart[t] = s0;
  __syncthreads();
  if (t == 0) {
    int run = 0;
    for (int i = 0; i < 1024; ++i) { int v = spart[i]; spart[i] = run; run += v; }
  }
  __syncthreads();
  const int off = spart[t];
#pragma unroll
  for (int i = 0; i < 8; ++i) { base[c0 + i] = off + loc[i]; cnts[c0 + i] = scnt[c0 + i]; }
  // my position: base[my] + rank (recompute base[my] from LDS)
  const int kb = my >> 3, kr = my & 7;
  int bb = spart[kb];
  for (int i = 0; i < kr; ++i) bb += scnt[(kb << 3) + i];
  list[bb + rank] = t;
}

// ---- cs chain fused: cs = 0.99cs+0.01cnt; ntot = np-pairwise(cs); smooth ----
__global__ __launch_bounds__(256) void cs_fused_kernel(float* __restrict__ cs,
                                                       const int* __restrict__ cnts,
                                                       float* __restrict__ nt) {
#pragma clang fp contract(off)
  __shared__ float scs[KCB];      // 32 KB
  __shared__ float s64v[64];
  const int t = threadIdx.x;
  for (int i = t; i < KCB; i += 256) {
    float a = 0.99f * cs[i];
    float b = 0.01f * (float)cnts[i];
    scs[i] = a + b;
  }
  __syncthreads();
  if (t < 64) s64v[t] = pw128(scs + t * 128);
  __syncthreads();
  if (t == 0) {
    float v[64];
    for (int i = 0; i < 64; ++i) v[i] = s64v[i];
    for (int len = 64; len > 1; len >>= 1)
      for (int i = 0; i < (len >> 1); ++i) v[i] = v[2*i] + v[2*i+1];
    nt[0] = v[0];
    s64v[0] = v[0];
  }
  __syncthreads();
  const float n = s64v[0];
  const float den = n + 0.08192f;          // f32(K*EPS)
  for (int i = t; i < KCB; i += 256) {
    float t1 = scs[i] + 1e-5f;
    float q = t1 / den;
    cs[i] = q * n;
  }
}

// ---- EMA fused: dw (CSR, ascending-b) + ew/cb update + cbsq pairwise -------
__global__ __launch_bounds__(256) void ema_fused_kernel(
    float* __restrict__ ew, const int* __restrict__ list,
    const int* __restrict__ base, const int* __restrict__ cnts,
    const float* __restrict__ zbuf, const float* __restrict__ cs,
    float* __restrict__ cb, float* __restrict__ cbsq)
{
#pragma clang fp contract(off)
  __shared__ float row2[256];
  const int k = blockIdx.x, d = threadIdx.x;
  const int start = base[k], cnt = cnts[k];
  float acc = 0.0f;
  for (int i = 0; i < cnt; ++i) {
    int b = list[start + i];
    acc += zbuf[(size_t)b * DDIM + d];     // ascending b == np.add.at order
  }
  const size_t o = (size_t)k * DDIM + d;
  float a = 0.99f * ew[o];
  float bb = 0.01f * acc;
  float e = a + bb;
  ew[o] = e;
  float c = e / cs[k];
  cb[o] = c;
  row2[d] = c * c;
  __syncthreads();
  if (d == 0) {
    float s0 = pw128(row2);
    float s1 = pw128(row2 + 128);
    cbsq[k] = s0 + s1;
  }
}

__global__ __launch_bounds__(256) void hfinal_kernel(const float* __restrict__ h,
                                                     float* __restrict__ out) {
  int i = blockIdx.x * 256 + threadIdx.x;
  out[OUT_HF + i] = h[i];
}

__global__ void loss_kernel(const float* __restrict__ loss_acc,
                            float* __restrict__ out) {
  out[OUT_LOSS] = 0.25f * (*loss_acc) / ((float)(BATCH * DDIM)) / (float)TSTEPS;
}

// ---------------- launch ----------------
extern "C" void kernel_launch(void* const* d_in, const int* in_sizes, int n_in,
                              void* d_out, int out_size, void* d_ws, size_t ws_size,
                              hipStream_t stream) {
  const float* sf    = (const float*)d_in[0];
  const float* bos   = (const float*)d_in[1];
  const float* W_ih  = (const float*)d_in[2];
  const float* W_hh  = (const float*)d_in[3];
  const float* b_ih  = (const float*)d_in[4];
  const float* b_hh  = (const float*)d_in[5];
  const float* Wg    = (const float*)d_in[6];
  const float* bg    = (const float*)d_in[7];
  const float* Wb    = (const float*)d_in[8];
  const float* bb    = (const float*)d_in[9];
  const float* W1    = (const float*)d_in[10];
  const float* b1    = (const float*)d_in[11];
  const float* W2    = (const float*)d_in[12];
  const float* b2    = (const float*)d_in[13];
  const float* cb_in = (const float*)d_in[14];
  const float* cs_in = (const float*)d_in[15];
  const float* ew_in = (const float*)d_in[16];

  float* ws  = (float*)d_ws;
  float* out = (float*)d_out;

  float* CB   = ws + WS_CB;
  float* EW   = ws + WS_EW;
  int*   LIST = (int*)(ws + WS_CSR);
  int*   BASE = LIST + BATCH;
  int*   CNTS = BASE + KCB;
  float* SM   = ws + WS_SM;
  float* H    = ws + WS_H;
  float* PREV = ws + WS_PREV;
  float* Z    = ws + WS_Z;
  float* GX   = ws + WS_GX;
  float* GH   = ws + WS_GH;
  float* GB   = ws + WS_GB;
  float* PIN  = ws + WS_PIN;
  float* H1   = ws + WS_H1;
  float* CS   = ws + WS_CS;
  float* CBSQ = ws + WS_CBSQ;
  float* SZZ  = ws + WS_SZZ;
  float* NT   = ws + WS_NT;
  float* LOSS = ws + WS_LOSS;
  int*   IDX  = (int*)(ws + WS_IDX);
  unsigned long long* ROWK = (unsigned long long*)(ws + WS_ROWK);
  float* WGWB = ws + WS_WGWB;
  float* BGBB = ws + WS_BGBB;

  // ---- per-launch init ----
  (void)hipMemcpyAsync(CB, cb_in, (size_t)KCB * DDIM * 4, hipMemcpyDeviceToDevice, stream);
  (void)hipMemcpyAsync(EW, ew_in, (size_t)KCB * DDIM * 4, hipMemcpyDeviceToDevice, stream);
  (void)hipMemcpyAsync(CS, cs_in, (size_t)KCB * 4, hipMemcpyDeviceToDevice, stream);
  (void)hipMemcpyAsync(WGWB, Wg, (size_t)CDIM * HD * 4, hipMemcpyDeviceToDevice, stream);
  (void)hipMemcpyAsync(WGWB + (size_t)CDIM * HD, Wb, (size_t)CDIM * HD * 4, hipMemcpyDeviceToDevice, stream);
  (void)hipMemcpyAsync(BGBB, bg, CDIM * 4, hipMemcpyDeviceToDevice, stream);
  (void)hipMemcpyAsync(BGBB + CDIM, bb, CDIM * 4, hipMemcpyDeviceToDevice, stream);
  (void)hipMemsetAsync(H, 0, (size_t)BATCH * HD * 4, stream);
  (void)hipMemsetAsync(LOSS, 0, 8, stream);
  previnit_kernel<<<BATCH * DDIM / 256, 256, 0, stream>>>(bos, PREV);
  smean_kernel<<<BATCH * CDIM / 256, 256, 0, stream>>>(sf, SM);
  pw256_rows_kernel<<<KCB / 256, 256, 0, stream>>>(CB, CBSQ, 1);

  for (int t = 0; t < TSTEPS; ++t) {
    (void)hipMemsetAsync(ROWK, 0xFF, BATCH * 8, stream);

    // GRU gates
    gemm_nt<false><<<dim3(16, G3/64), 256, 0, stream>>>(PREV, DDIM, W_ih, DDIM, GX, G3, b_ih, DDIM);
    gemm_nt<false><<<dim3(16, G3/64), 256, 0, stream>>>(H, HD, W_hh, HD, GH, G3, b_hh, HD);
    gru_kernel<<<BATCH * HD / 256, 256, 0, stream>>>(GX, GH, H);

    // FiLM + pin
    gemm_nt<false><<<dim3(16, 1024/64), 256, 0, stream>>>(H, HD, WGWB, HD, GB, 1024, BGBB, HD);
    film_kernel<<<BATCH * CDIM / 256, 256, 0, stream>>>(GB, SM, H, PIN);

    // MLP
    gemm_nt<true ><<<dim3(16, HD/64), 256, 0, stream>>>(PIN, 1024, W1, 1024, H1, HD, b1, 1024);
    gemm_nt<false><<<dim3(16, DDIM/64), 256, 0, stream>>>(H1, HD, W2, HD, Z, DDIM, b2, HD);

    // VQ
    pw256_rows_kernel<<<BATCH / 256, 256, 0, stream>>>(Z, SZZ, 1);
    gemm_score_argmin<<<dim3(16, KCB/64), 256, 0, stream>>>(Z, CB, CBSQ, SZZ, ROWK);
    vq_apply_kernel<<<BATCH, 256, 0, stream>>>(ROWK, CB, Z, PREV, IDX, LOSS, out, t);

    // EMA via CSR (deterministic np.add.at order), cs chain fused, cbsq fused
    csr_build_kernel<<<1, 1024, 0, stream>>>(IDX, LIST, BASE, CNTS);
    cs_fused_kernel<<<1, 256, 0, stream>>>(CS, CNTS, NT);
    ema_fused_kernel<<<KCB, 256, 0, stream>>>(EW, LIST, BASE, CNTS, Z, CS, CB, CBSQ);
  }

  hfinal_kernel<<<BATCH * HD / 256, 256, 0, stream>>>(H, out);
  loss_kernel<<<1, 1, 0, stream>>>(LOSS, out);
}

// Round 9
// 2809.737 us; speedup vs baseline: 1.5247x; 1.0341x over previous
//
#include <hip/hip_runtime.h>

#define BATCH 1024
#define CDIM  512
#define DDIM  256
#define KCB   8192
#define HD    512
#define G3    1536
#define TSTEPS 8

// ---------------- workspace layout (float offsets) ----------------
#define WS_CB    ((size_t)0)          // [K,D]
#define WS_EW    ((size_t)2097152)    // [K,D]
#define WS_CSR   ((size_t)4194304)    // ints: list[1024] | base[8192] | cnts[8192]
#define WS_SM    ((size_t)6291456)    // [B,C]
#define WS_H     ((size_t)6815744)    // [B,HD]
#define WS_PREV  ((size_t)7340032)    // [B,D]
#define WS_Z     ((size_t)7602176)    // [B,D]
#define WS_GX    ((size_t)7864320)    // [B,3HD]
#define WS_GH    ((size_t)9437184)    // [B,3HD]
#define WS_GB    ((size_t)11010048)   // [B,1024]
#define WS_PIN   ((size_t)12058624)   // [B,1024]
#define WS_H1    ((size_t)13107200)   // [B,HD]
#define WS_CS    ((size_t)13631488)   // [K]
#define WS_CBSQ  ((size_t)13639680)   // [K]
#define WS_SZZ   ((size_t)13647872)   // [B]
#define WS_NT    ((size_t)13657088)   // [1]+pad
#define WS_LOSS  ((size_t)13657090)   // [1]+pad
#define WS_IDX   ((size_t)13657092)   // [B] ints
#define WS_ROWK  ((size_t)13658116)   // [B] u64 (8B-aligned)
#define WS_WGWB  ((size_t)13660164)   // [1024,512]
#define WS_BGBB  ((size_t)14184452)   // [1024]

// ---------------- output layout (f32 elements) ----------------
#define OUT_HF    ((size_t)0)
#define OUT_CODES ((size_t)524288)
#define OUT_IDX   ((size_t)2621440)
#define OUT_ZC    ((size_t)2629632)
#define OUT_LOSS  ((size_t)4726784)

// order-preserving map of f32 bits; col in low 32 bits -> ties pick lowest col
static __device__ __forceinline__ unsigned long long key32(float s, int col) {
  unsigned int u = __float_as_uint(s);
  u = (u & 0x80000000u) ? ~u : (u | 0x80000000u);
  return (((unsigned long long)u) << 32) | (unsigned long long)(unsigned int)col;
}

// numpy pairwise_sum for n=128 block: 8 accumulators, tree combine
static __device__ __forceinline__ float pw128(const float* a) {
  float r0=a[0],r1=a[1],r2=a[2],r3=a[3],r4=a[4],r5=a[5],r6=a[6],r7=a[7];
  for (int i = 8; i < 128; i += 8) {
    r0+=a[i+0]; r1+=a[i+1]; r2+=a[i+2]; r3+=a[i+3];
    r4+=a[i+4]; r5+=a[i+5]; r6+=a[i+6]; r7+=a[i+7];
  }
  return ((r0+r1)+(r2+r3))+((r4+r5)+(r6+r7));
}
// numpy pairwise for n=256: split 128+128 (optionally square elements)
static __device__ __forceinline__ float pw256sq(const float* a, bool square) {
#pragma clang fp contract(off)
  float buf[128];
  if (square) { for (int i=0;i<128;++i){float v=a[i];buf[i]=v*v;} }
  else        { for (int i=0;i<128;++i) buf[i]=a[i]; }
  float s0 = pw128(buf);
  if (square) { for (int i=0;i<128;++i){float v=a[128+i];buf[i]=v*v;} }
  else        { for (int i=0;i<128;++i) buf[i]=a[128+i]; }
  float s1 = pw128(buf);
  return s0 + s1;
}

// ---------------- f32 GEMM 64x64 (TM=TN=4), k-ascending fmaf chain ----------
template<bool RELU>
__global__ __launch_bounds__(256) void gemm_nt(
    const float* __restrict__ A, int lda,
    const float* __restrict__ B, int ldb,
    float* __restrict__ C, int ldc,
    const float* __restrict__ bias, int K)
{
  __shared__ float As[16][68];
  __shared__ float Bs[16][68];
  const int tid = threadIdx.x;
  const int tx = tid & 15, ty = tid >> 4;
  const int m0 = blockIdx.x * 64, n0 = blockIdx.y * 64;
  const int lr = tid >> 2, lq = tid & 3;
  const float4* Ab = (const float4*)(A + (size_t)(m0 + lr) * lda);
  const float4* Bb = (const float4*)(B + (size_t)(n0 + lr) * ldb);
  float acc[4][4] = {};
  for (int k0 = 0; k0 < K; k0 += 16) {
    float4 av = Ab[(k0 >> 2) + lq];
    float4 bv = Bb[(k0 >> 2) + lq];
    __syncthreads();
    As[lq*4+0][lr] = av.x; As[lq*4+1][lr] = av.y;
    As[lq*4+2][lr] = av.z; As[lq*4+3][lr] = av.w;
    Bs[lq*4+0][lr] = bv.x; Bs[lq*4+1][lr] = bv.y;
    Bs[lq*4+2][lr] = bv.z; Bs[lq*4+3][lr] = bv.w;
    __syncthreads();
#pragma unroll
    for (int kk = 0; kk < 16; ++kk) {
      float4 a = *(const float4*)&As[kk][ty*4];
      float4 b = *(const float4*)&Bs[kk][tx*4];
      acc[0][0]=fmaf(a.x,b.x,acc[0][0]); acc[0][1]=fmaf(a.x,b.y,acc[0][1]); acc[0][2]=fmaf(a.x,b.z,acc[0][2]); acc[0][3]=fmaf(a.x,b.w,acc[0][3]);
      acc[1][0]=fmaf(a.y,b.x,acc[1][0]); acc[1][1]=fmaf(a.y,b.y,acc[1][1]); acc[1][2]=fmaf(a.y,b.z,acc[1][2]); acc[1][3]=fmaf(a.y,b.w,acc[1][3]);
      acc[2][0]=fmaf(a.z,b.x,acc[2][0]); acc[2][1]=fmaf(a.z,b.y,acc[2][1]); acc[2][2]=fmaf(a.z,b.z,acc[2][2]); acc[2][3]=fmaf(a.z,b.w,acc[2][3]);
      acc[3][0]=fmaf(a.w,b.x,acc[3][0]); acc[3][1]=fmaf(a.w,b.y,acc[3][1]); acc[3][2]=fmaf(a.w,b.z,acc[3][2]); acc[3][3]=fmaf(a.w,b.w,acc[3][3]);
    }
  }
  {
#pragma clang fp contract(off)
#pragma unroll
    for (int i = 0; i < 4; ++i) {
#pragma unroll
      for (int j = 0; j < 4; ++j) {
        float v = acc[i][j] + bias[n0 + tx*4 + j];
        if (RELU) v = fmaxf(v, 0.0f);
        C[(size_t)(m0 + ty*4 + i) * ldc + n0 + tx*4 + j] = v;
      }
    }
  }
}

// --------- VQ: G = z.cb_k (sgemm-order chain); d = (szz - 2G) + scb; argmin --
__global__ __launch_bounds__(256) void gemm_score_argmin(
    const float* __restrict__ A,      // z [B,D]
    const float* __restrict__ Bc,     // cb [K,D]
    const float* __restrict__ cbsq,   // [K]
    const float* __restrict__ szz,    // [B]
    unsigned long long* __restrict__ rowkeys)
{
  __shared__ float As[16][68];
  __shared__ float Bs[16][68];
  __shared__ unsigned long long Ks[64][17];
  const int tid = threadIdx.x;
  const int tx = tid & 15, ty = tid >> 4;
  const int m0 = blockIdx.x * 64, n0 = blockIdx.y * 64;
  const int lr = tid >> 2, lq = tid & 3;
  const float4* Ab = (const float4*)(A + (size_t)(m0 + lr) * DDIM);
  const float4* Bb = (const float4*)(Bc + (size_t)(n0 + lr) * DDIM);
  float acc[4][4] = {};
  for (int k0 = 0; k0 < DDIM; k0 += 16) {
    float4 av = Ab[(k0 >> 2) + lq];
    float4 bv = Bb[(k0 >> 2) + lq];
    __syncthreads();
    As[lq*4+0][lr] = av.x; As[lq*4+1][lr] = av.y;
    As[lq*4+2][lr] = av.z; As[lq*4+3][lr] = av.w;
    Bs[lq*4+0][lr] = bv.x; Bs[lq*4+1][lr] = bv.y;
    Bs[lq*4+2][lr] = bv.z; Bs[lq*4+3][lr] = bv.w;
    __syncthreads();
#pragma unroll
    for (int kk = 0; kk < 16; ++kk) {
      float4 a = *(const float4*)&As[kk][ty*4];
      float4 b = *(const float4*)&Bs[kk][tx*4];
      acc[0][0]=fmaf(a.x,b.x,acc[0][0]); acc[0][1]=fmaf(a.x,b.y,acc[0][1]); acc[0][2]=fmaf(a.x,b.z,acc[0][2]); acc[0][3]=fmaf(a.x,b.w,acc[0][3]);
      acc[1][0]=fmaf(a.y,b.x,acc[1][0]); acc[1][1]=fmaf(a.y,b.y,acc[1][1]); acc[1][2]=fmaf(a.y,b.z,acc[1][2]); acc[1][3]=fmaf(a.y,b.w,acc[1][3]);
      acc[2][0]=fmaf(a.z,b.x,acc[2][0]); acc[2][1]=fmaf(a.z,b.y,acc[2][1]); acc[2][2]=fmaf(a.z,b.z,acc[2][2]); acc[2][3]=fmaf(a.z,b.w,acc[2][3]);
      acc[3][0]=fmaf(a.w,b.x,acc[3][0]); acc[3][1]=fmaf(a.w,b.y,acc[3][1]); acc[3][2]=fmaf(a.w,b.z,acc[3][2]); acc[3][3]=fmaf(a.w,b.w,acc[3][3]);
    }
  }
  {
#pragma clang fp contract(off)
    const int nb = n0 + tx * 4;
#pragma unroll
    for (int i = 0; i < 4; ++i) {
      float sz = szz[m0 + ty*4 + i];
      unsigned long long kb[4];
#pragma unroll
      for (int j = 0; j < 4; ++j) {
        float g2 = 2.0f * acc[i][j];     // exact (pow2 scale)
        float t1 = sz - g2;              // np: (szz - 2G)
        float d  = t1 + cbsq[nb + j];    // np: ... + scb
        kb[j] = key32(d, nb + j);
      }
      unsigned long long ka = kb[0] < kb[1] ? kb[0] : kb[1];
      unsigned long long kc = kb[2] < kb[3] ? kb[2] : kb[3];
      Ks[ty*4 + i][tx] = ka < kc ? ka : kc;
    }
  }
  __syncthreads();
  if (tid < 64) {
    unsigned long long best = Ks[tid][0];
#pragma unroll
    for (int t = 1; t < 16; ++t) {
      unsigned long long v = Ks[tid][t];
      best = v < best ? v : best;
    }
    atomicMin(&rowkeys[m0 + tid], best);
  }
}

// ---------------- elementwise / reduction kernels (np-f32 faithful) ---------
__global__ __launch_bounds__(256) void pw256_rows_kernel(const float* __restrict__ src,
                                                         float* __restrict__ dst,
                                                         int square) {
  int r = blockIdx.x * 256 + threadIdx.x;
  dst[r] = pw256sq(src + (size_t)r * 256, square != 0);
}

__global__ __launch_bounds__(256) void smean_kernel(const float* __restrict__ sf,
                                                    float* __restrict__ sm) {
#pragma clang fp contract(off)
  int i = blockIdx.x * 256 + threadIdx.x;     // B*C threads
  const float* a = sf + (size_t)i * 49;
  float r0=a[0],r1=a[1],r2=a[2],r3=a[3],r4=a[4],r5=a[5],r6=a[6],r7=a[7];
  for (int k = 8; k < 48; k += 8) {
    r0+=a[k+0]; r1+=a[k+1]; r2+=a[k+2]; r3+=a[k+3];
    r4+=a[k+4]; r5+=a[k+5]; r6+=a[k+6]; r7+=a[k+7];
  }
  float res = ((r0+r1)+(r2+r3))+((r4+r5)+(r6+r7));
  res += a[48];
  sm[i] = res / 49.0f;
}

__global__ __launch_bounds__(256) void previnit_kernel(const float* __restrict__ bos,
                                                       float* __restrict__ prev) {
  int i = blockIdx.x * 256 + threadIdx.x;
  prev[i] = bos[i & (DDIM - 1)];
}

__global__ __launch_bounds__(256) void gru_kernel(const float* __restrict__ gx,
                                                  const float* __restrict__ gh,
                                                  float* __restrict__ h) {
#pragma clang fp contract(off)
  int i = blockIdx.x * 256 + threadIdx.x;
  int b = i >> 9, j = i & 511;
  size_t o = (size_t)b * G3;
  float xr = gx[o + j], xz = gx[o + 512 + j], xn = gx[o + 1024 + j];
  float hr = gh[o + j], hz = gh[o + 512 + j], hn = gh[o + 1024 + j];
  float ar = xr + hr;
  float az = xz + hz;
  float er = expf(-ar);
  float ez = expf(-az);
  float r  = 1.0f / (1.0f + er);
  float zz = 1.0f / (1.0f + ez);
  float rh = r * hn;
  float an = xn + rh;
  float n  = tanhf(an);
  float hold = h[i];
  float t1 = (1.0f - zz) * n;
  float t2 = zz * hold;
  h[i] = t1 + t2;
}

__global__ __launch_bounds__(256) void film_kernel(const float* __restrict__ gb,
                                                   const float* __restrict__ sm,
                                                   const float* __restrict__ h,
                                                   float* __restrict__ pin) {
#pragma clang fp contract(off)
  int i = blockIdx.x * 256 + threadIdx.x;
  int b = i >> 9, j = i & 511;
  float gamma = gb[(size_t)b * 1024 + j];
  float beta  = gb[(size_t)b * 1024 + 512 + j];
  float t1 = 1.0f + gamma;
  float t2 = t1 * sm[i];
  float cval = t2 + beta;
  pin[(size_t)b * 1024 + j] = h[i];
  pin[(size_t)b * 1024 + 512 + j] = cval;
}

__global__ __launch_bounds__(256) void vq_apply_kernel(
    const unsigned long long* __restrict__ rowkeys,
    const float* __restrict__ cb, const float* __restrict__ zbuf,
    float* __restrict__ prev, int* __restrict__ idxarr,
    float* __restrict__ loss_acc, float* __restrict__ out, int t)
{
#pragma clang fp contract(off)
  int b = blockIdx.x, d = threadIdx.x;
  int idx = (int)(rowkeys[b] & 0xFFFFFFFFull);
  float zq = cb[(size_t)idx * DDIM + d];
  float zb = zbuf[(size_t)b * DDIM + d];
  float delta = zq - zb;
  float zste = zb + delta;                  // z + (z_q - z)
  size_t td = ((size_t)b * TSTEPS + t) * DDIM + d;
  out[OUT_CODES + td] = zste;
  out[OUT_ZC + td] = zb;
  prev[(size_t)b * DDIM + d] = zste;
  if (d == 0) {
    idxarr[b] = idx;
    out[OUT_IDX + (size_t)b * TSTEPS + t] = (float)idx;
  }
  float diff = zb - zq;
  __shared__ float red[256];
  red[d] = diff * diff; __syncthreads();
  for (int s = 128; s > 0; s >>= 1) { if (d < s) red[d] += red[d + s]; __syncthreads(); }
  if (d == 0) atomicAdd(loss_acc, red[0]);
}

// ---- CSR bucket build: rank within equal idx (ascending b == np.add.at order)
__global__ __launch_bounds__(1024) void csr_build_kernel(const int* __restrict__ idxarr,
                                                         int* __restrict__ list,
                                                         int* __restrict__ base,
                                                         int* __restrict__ cnts) {
  __shared__ int sidx[BATCH];
  __shared__ int scnt[KCB];       // 32 KB
  __shared__ int spart[1024];
  const int t = threadIdx.x;
  sidx[t] = idxarr[t];
  for (int i = t; i < KCB; i += 1024) scnt[i] = 0;
  __syncthreads();
  const int my = sidx[t];
  atomicAdd(&scnt[my], 1);
  int rank = 0;
  for (int b = 0; b < t; ++b) rank += (sidx[b] == my) ? 1 : 0;
  __syncthreads();
  const int c0 = t * 8;
  int loc[8]; int s0 = 0;
#pragma unroll
  for (int i = 0; i < 8; ++i) { loc[i] = s0; s0 += scnt[c0 + i]; }
  spart[t] = s0;
  __syncthreads();
  if (t == 0) {
    int run = 0;
    for (int i = 0; i < 1024; ++i) { int v = spart[i]; spart[i] = run; run += v; }
  }
  __syncthreads();
  const int off = spart[t];
#pragma unroll
  for (int i = 0; i < 8; ++i) { base[c0 + i] = off + loc[i]; cnts[c0 + i] = scnt[c0 + i]; }
  const int kb = my >> 3, kr = my & 7;
  int bb = spart[kb];
  for (int i = 0; i < kr; ++i) bb += scnt[(kb << 3) + i];
  list[bb + rank] = t;
}

// ---- cs chain fused: cs = 0.99cs+0.01cnt; ntot = np-pairwise(cs); smooth ----
__global__ __launch_bounds__(256) void cs_fused_kernel(float* __restrict__ cs,
                                                       const int* __restrict__ cnts,
                                                       float* __restrict__ nt) {
#pragma clang fp contract(off)
  __shared__ float scs[KCB];      // 32 KB
  __shared__ float s64v[64];
  const int t = threadIdx.x;
  for (int i = t; i < KCB; i += 256) {
    float a = 0.99f * cs[i];
    float b = 0.01f * (float)cnts[i];
    scs[i] = a + b;
  }
  __syncthreads();
  if (t < 64) s64v[t] = pw128(scs + t * 128);
  __syncthreads();
  if (t == 0) {
    float v[64];
    for (int i = 0; i < 64; ++i) v[i] = s64v[i];
    for (int len = 64; len > 1; len >>= 1)
      for (int i = 0; i < (len >> 1); ++i) v[i] = v[2*i] + v[2*i+1];
    nt[0] = v[0];
    s64v[0] = v[0];
  }
  __syncthreads();
  const float n = s64v[0];
  const float den = n + 0.08192f;          // f32(K*EPS)
  for (int i = t; i < KCB; i += 256) {
    float t1 = scs[i] + 1e-5f;
    float q = t1 / den;
    cs[i] = q * n;
  }
}

// ---- EMA fused v3: 8 rows/block (1024 blocks); dw gather (CSR, ascending b)
// + ew/cb update + cbsq. cbsq tail: 16 threads compute numpy pw128's 16
// accumulator chains (exact numpy order), thread 0 does the exact tree combine.
__global__ __launch_bounds__(256) void ema_fused_kernel(
    float* __restrict__ ew, const int* __restrict__ list,
    const int* __restrict__ base, const int* __restrict__ cnts,
    const float* __restrict__ zbuf, const float* __restrict__ cs,
    float* __restrict__ cb, float* __restrict__ cbsq)
{
#pragma clang fp contract(off)
  __shared__ float row2[256];
  __shared__ float ch[16];
  const int d = threadIdx.x;
  for (int r = 0; r < 8; ++r) {
    const int k = blockIdx.x * 8 + r;
    const int start = base[k], cnt = cnts[k];
    float acc = 0.0f;
    for (int i = 0; i < cnt; ++i) {
      int b = list[start + i];
      acc += zbuf[(size_t)b * DDIM + d];   // ascending b == np.add.at order
    }
    const size_t o = (size_t)k * DDIM + d;
    float a = 0.99f * ew[o];
    float bb = 0.01f * acc;
    float e = a + bb;
    ew[o] = e;
    float c = e / cs[k];
    cb[o] = c;
    row2[d] = c * c;
    __syncthreads();
    if (d < 16) {
      int h = d >> 3, j = d & 7;
      const float* p = row2 + h * 128 + j;
      float rr = p[0];
      for (int i = 1; i < 16; ++i) rr += p[8 * i];
      ch[d] = rr;
    }
    __syncthreads();
    if (d == 0) {
      float s0 = ((ch[0]+ch[1])+(ch[2]+ch[3]))+((ch[4]+ch[5])+(ch[6]+ch[7]));
      float s1 = ((ch[8]+ch[9])+(ch[10]+ch[11]))+((ch[12]+ch[13])+(ch[14]+ch[15]));
      cbsq[k] = s0 + s1;
    }
    __syncthreads();
  }
}

__global__ __launch_bounds__(256) void hfinal_kernel(const float* __restrict__ h,
                                                     float* __restrict__ out) {
  int i = blockIdx.x * 256 + threadIdx.x;
  out[OUT_HF + i] = h[i];
}

__global__ void loss_kernel(const float* __restrict__ loss_acc,
                            float* __restrict__ out) {
  out[OUT_LOSS] = 0.25f * (*loss_acc) / ((float)(BATCH * DDIM)) / (float)TSTEPS;
}

// ---------------- launch ----------------
extern "C" void kernel_launch(void* const* d_in, const int* in_sizes, int n_in,
                              void* d_out, int out_size, void* d_ws, size_t ws_size,
                              hipStream_t stream) {
  const float* sf    = (const float*)d_in[0];
  const float* bos   = (const float*)d_in[1];
  const float* W_ih  = (const float*)d_in[2];
  const float* W_hh  = (const float*)d_in[3];
  const float* b_ih  = (const float*)d_in[4];
  const float* b_hh  = (const float*)d_in[5];
  const float* Wg    = (const float*)d_in[6];
  const float* bg    = (const float*)d_in[7];
  const float* Wb    = (const float*)d_in[8];
  const float* bb    = (const float*)d_in[9];
  const float* W1    = (const float*)d_in[10];
  const float* b1    = (const float*)d_in[11];
  const float* W2    = (const float*)d_in[12];
  const float* b2    = (const float*)d_in[13];
  const float* cb_in = (const float*)d_in[14];
  const float* cs_in = (const float*)d_in[15];
  const float* ew_in = (const float*)d_in[16];

  float* ws  = (float*)d_ws;
  float* out = (float*)d_out;

  float* CB   = ws + WS_CB;
  float* EW   = ws + WS_EW;
  int*   LIST = (int*)(ws + WS_CSR);
  int*   BASE = LIST + BATCH;
  int*   CNTS = BASE + KCB;
  float* SM   = ws + WS_SM;
  float* H    = ws + WS_H;
  float* PREV = ws + WS_PREV;
  float* Z    = ws + WS_Z;
  float* GX   = ws + WS_GX;
  float* GH   = ws + WS_GH;
  float* GB   = ws + WS_GB;
  float* PIN  = ws + WS_PIN;
  float* H1   = ws + WS_H1;
  float* CS   = ws + WS_CS;
  float* CBSQ = ws + WS_CBSQ;
  float* SZZ  = ws + WS_SZZ;
  float* NT   = ws + WS_NT;
  float* LOSS = ws + WS_LOSS;
  int*   IDX  = (int*)(ws + WS_IDX);
  unsigned long long* ROWK = (unsigned long long*)(ws + WS_ROWK);
  float* WGWB = ws + WS_WGWB;
  float* BGBB = ws + WS_BGBB;

  // ---- per-launch init ----
  (void)hipMemcpyAsync(CB, cb_in, (size_t)KCB * DDIM * 4, hipMemcpyDeviceToDevice, stream);
  (void)hipMemcpyAsync(EW, ew_in, (size_t)KCB * DDIM * 4, hipMemcpyDeviceToDevice, stream);
  (void)hipMemcpyAsync(CS, cs_in, (size_t)KCB * 4, hipMemcpyDeviceToDevice, stream);
  (void)hipMemcpyAsync(WGWB, Wg, (size_t)CDIM * HD * 4, hipMemcpyDeviceToDevice, stream);
  (void)hipMemcpyAsync(WGWB + (size_t)CDIM * HD, Wb, (size_t)CDIM * HD * 4, hipMemcpyDeviceToDevice, stream);
  (void)hipMemcpyAsync(BGBB, bg, CDIM * 4, hipMemcpyDeviceToDevice, stream);
  (void)hipMemcpyAsync(BGBB + CDIM, bb, CDIM * 4, hipMemcpyDeviceToDevice, stream);
  (void)hipMemsetAsync(H, 0, (size_t)BATCH * HD * 4, stream);
  (void)hipMemsetAsync(LOSS, 0, 8, stream);
  previnit_kernel<<<BATCH * DDIM / 256, 256, 0, stream>>>(bos, PREV);
  smean_kernel<<<BATCH * CDIM / 256, 256, 0, stream>>>(sf, SM);
  pw256_rows_kernel<<<KCB / 256, 256, 0, stream>>>(CB, CBSQ, 1);

  for (int t = 0; t < TSTEPS; ++t) {
    (void)hipMemsetAsync(ROWK, 0xFF, BATCH * 8, stream);

    // GRU gates
    gemm_nt<false><<<dim3(16, G3/64), 256, 0, stream>>>(PREV, DDIM, W_ih, DDIM, GX, G3, b_ih, DDIM);
    gemm_nt<false><<<dim3(16, G3/64), 256, 0, stream>>>(H, HD, W_hh, HD, GH, G3, b_hh, HD);
    gru_kernel<<<BATCH * HD / 256, 256, 0, stream>>>(GX, GH, H);

    // FiLM + pin
    gemm_nt<false><<<dim3(16, 1024/64), 256, 0, stream>>>(H, HD, WGWB, HD, GB, 1024, BGBB, HD);
    film_kernel<<<BATCH * CDIM / 256, 256, 0, stream>>>(GB, SM, H, PIN);

    // MLP
    gemm_nt<true ><<<dim3(16, HD/64), 256, 0, stream>>>(PIN, 1024, W1, 1024, H1, HD, b1, 1024);
    gemm_nt<false><<<dim3(16, DDIM/64), 256, 0, stream>>>(H1, HD, W2, HD, Z, DDIM, b2, HD);

    // VQ
    pw256_rows_kernel<<<BATCH / 256, 256, 0, stream>>>(Z, SZZ, 1);
    gemm_score_argmin<<<dim3(16, KCB/64), 256, 0, stream>>>(Z, CB, CBSQ, SZZ, ROWK);
    vq_apply_kernel<<<BATCH, 256, 0, stream>>>(ROWK, CB, Z, PREV, IDX, LOSS, out, t);

    // EMA via CSR (deterministic np.add.at order)
    csr_build_kernel<<<1, 1024, 0, stream>>>(IDX, LIST, BASE, CNTS);
    cs_fused_kernel<<<1, 256, 0, stream>>>(CS, CNTS, NT);
    ema_fused_kernel<<<KCB/8, 256, 0, stream>>>(EW, LIST, BASE, CNTS, Z, CS, CB, CBSQ);
  }

  hfinal_kernel<<<BATCH * HD / 256, 256, 0, stream>>>(H, out);
  loss_kernel<<<1, 1, 0, stream>>>(LOSS, out);
}

// Round 10
// 2619.536 us; speedup vs baseline: 1.6354x; 1.0726x over previous
//
#include <hip/hip_runtime.h>

#define BATCH 1024
#define CDIM  512
#define DDIM  256
#define KCB   8192
#define HD    512
#define G3    1536
#define TSTEPS 8

// ---------------- workspace layout (float offsets) ----------------
#define WS_CB    ((size_t)0)          // [K,D]
#define WS_EW    ((size_t)2097152)    // [K,D]
#define WS_CSR   ((size_t)4194304)    // ints: list[1024] | base[8192] | cnts[8192]
#define WS_SM    ((size_t)6291456)    // [B,C]
#define WS_H     ((size_t)6815744)    // [B,HD]
#define WS_PREV  ((size_t)7340032)    // [B,D]
#define WS_Z     ((size_t)7602176)    // [B,D]
#define WS_GX    ((size_t)7864320)    // [B,3HD]
#define WS_GH    ((size_t)9437184)    // [B,3HD]
#define WS_GB    ((size_t)11010048)   // [B,1024]
#define WS_PIN   ((size_t)12058624)   // [B,1024]
#define WS_H1    ((size_t)13107200)   // [B,HD]
#define WS_CS    ((size_t)13631488)   // [K]
#define WS_CBSQ  ((size_t)13639680)   // [K]
#define WS_SZZ   ((size_t)13647872)   // [B]
#define WS_NT    ((size_t)13657088)   // [1]+pad
#define WS_LOSS  ((size_t)13657090)   // [1]+pad
#define WS_IDX   ((size_t)13657092)   // [B] ints
#define WS_ROWK  ((size_t)13658116)   // [B] u64 (8B-aligned)
#define WS_WGWB  ((size_t)13660164)   // [1024,512]
#define WS_BGBB  ((size_t)14184452)   // [1024]

// ---------------- output layout (f32 elements) ----------------
#define OUT_HF    ((size_t)0)
#define OUT_CODES ((size_t)524288)
#define OUT_IDX   ((size_t)2621440)
#define OUT_ZC    ((size_t)2629632)
#define OUT_LOSS  ((size_t)4726784)

// order-preserving map of f32 bits; col in low 32 bits -> ties pick lowest col
static __device__ __forceinline__ unsigned long long key32(float s, int col) {
  unsigned int u = __float_as_uint(s);
  u = (u & 0x80000000u) ? ~u : (u | 0x80000000u);
  return (((unsigned long long)u) << 32) | (unsigned long long)(unsigned int)col;
}

// numpy pairwise_sum for n=128 block: 8 accumulators, tree combine
static __device__ __forceinline__ float pw128(const float* a) {
  float r0=a[0],r1=a[1],r2=a[2],r3=a[3],r4=a[4],r5=a[5],r6=a[6],r7=a[7];
  for (int i = 8; i < 128; i += 8) {
    r0+=a[i+0]; r1+=a[i+1]; r2+=a[i+2]; r3+=a[i+3];
    r4+=a[i+4]; r5+=a[i+5]; r6+=a[i+6]; r7+=a[i+7];
  }
  return ((r0+r1)+(r2+r3))+((r4+r5)+(r6+r7));
}
// numpy pairwise for n=256: split 128+128 (optionally square elements)
static __device__ __forceinline__ float pw256sq(const float* a, bool square) {
#pragma clang fp contract(off)
  float buf[128];
  if (square) { for (int i=0;i<128;++i){float v=a[i];buf[i]=v*v;} }
  else        { for (int i=0;i<128;++i) buf[i]=a[i]; }
  float s0 = pw128(buf);
  if (square) { for (int i=0;i<128;++i){float v=a[128+i];buf[i]=v*v;} }
  else        { for (int i=0;i<128;++i) buf[i]=a[128+i]; }
  float s1 = pw128(buf);
  return s0 + s1;
}

// ---------------- f32 GEMM 64x64 (TM=TN=4), k-ascending fmaf chain ----------
template<bool RELU>
__global__ __launch_bounds__(256) void gemm_nt(
    const float* __restrict__ A, int lda,
    const float* __restrict__ B, int ldb,
    float* __restrict__ C, int ldc,
    const float* __restrict__ bias, int K)
{
  __shared__ float As[16][68];
  __shared__ float Bs[16][68];
  const int tid = threadIdx.x;
  const int tx = tid & 15, ty = tid >> 4;
  const int m0 = blockIdx.x * 64, n0 = blockIdx.y * 64;
  const int lr = tid >> 2, lq = tid & 3;
  const float4* Ab = (const float4*)(A + (size_t)(m0 + lr) * lda);
  const float4* Bb = (const float4*)(B + (size_t)(n0 + lr) * ldb);
  float acc[4][4] = {};
  for (int k0 = 0; k0 < K; k0 += 16) {
    float4 av = Ab[(k0 >> 2) + lq];
    float4 bv = Bb[(k0 >> 2) + lq];
    __syncthreads();
    As[lq*4+0][lr] = av.x; As[lq*4+1][lr] = av.y;
    As[lq*4+2][lr] = av.z; As[lq*4+3][lr] = av.w;
    Bs[lq*4+0][lr] = bv.x; Bs[lq*4+1][lr] = bv.y;
    Bs[lq*4+2][lr] = bv.z; Bs[lq*4+3][lr] = bv.w;
    __syncthreads();
#pragma unroll
    for (int kk = 0; kk < 16; ++kk) {
      float4 a = *(const float4*)&As[kk][ty*4];
      float4 b = *(const float4*)&Bs[kk][tx*4];
      acc[0][0]=fmaf(a.x,b.x,acc[0][0]); acc[0][1]=fmaf(a.x,b.y,acc[0][1]); acc[0][2]=fmaf(a.x,b.z,acc[0][2]); acc[0][3]=fmaf(a.x,b.w,acc[0][3]);
      acc[1][0]=fmaf(a.y,b.x,acc[1][0]); acc[1][1]=fmaf(a.y,b.y,acc[1][1]); acc[1][2]=fmaf(a.y,b.z,acc[1][2]); acc[1][3]=fmaf(a.y,b.w,acc[1][3]);
      acc[2][0]=fmaf(a.z,b.x,acc[2][0]); acc[2][1]=fmaf(a.z,b.y,acc[2][1]); acc[2][2]=fmaf(a.z,b.z,acc[2][2]); acc[2][3]=fmaf(a.z,b.w,acc[2][3]);
      acc[3][0]=fmaf(a.w,b.x,acc[3][0]); acc[3][1]=fmaf(a.w,b.y,acc[3][1]); acc[3][2]=fmaf(a.w,b.z,acc[3][2]); acc[3][3]=fmaf(a.w,b.w,acc[3][3]);
    }
  }
  {
#pragma clang fp contract(off)
#pragma unroll
    for (int i = 0; i < 4; ++i) {
#pragma unroll
      for (int j = 0; j < 4; ++j) {
        float v = acc[i][j] + bias[n0 + tx*4 + j];
        if (RELU) v = fmaxf(v, 0.0f);
        C[(size_t)(m0 + ty*4 + i) * ldc + n0 + tx*4 + j] = v;
      }
    }
  }
}

// --------- VQ: G = z.cb_k (sgemm-order chain); d = (szz - 2G) + scb; argmin --
__global__ __launch_bounds__(256) void gemm_score_argmin(
    const float* __restrict__ A,      // z [B,D]
    const float* __restrict__ Bc,     // cb [K,D]
    const float* __restrict__ cbsq,   // [K]
    const float* __restrict__ szz,    // [B]
    unsigned long long* __restrict__ rowkeys)
{
  __shared__ float As[16][68];
  __shared__ float Bs[16][68];
  __shared__ unsigned long long Ks[64][17];
  const int tid = threadIdx.x;
  const int tx = tid & 15, ty = tid >> 4;
  const int m0 = blockIdx.x * 64, n0 = blockIdx.y * 64;
  const int lr = tid >> 2, lq = tid & 3;
  const float4* Ab = (const float4*)(A + (size_t)(m0 + lr) * DDIM);
  const float4* Bb = (const float4*)(Bc + (size_t)(n0 + lr) * DDIM);
  float acc[4][4] = {};
  for (int k0 = 0; k0 < DDIM; k0 += 16) {
    float4 av = Ab[(k0 >> 2) + lq];
    float4 bv = Bb[(k0 >> 2) + lq];
    __syncthreads();
    As[lq*4+0][lr] = av.x; As[lq*4+1][lr] = av.y;
    As[lq*4+2][lr] = av.z; As[lq*4+3][lr] = av.w;
    Bs[lq*4+0][lr] = bv.x; Bs[lq*4+1][lr] = bv.y;
    Bs[lq*4+2][lr] = bv.z; Bs[lq*4+3][lr] = bv.w;
    __syncthreads();
#pragma unroll
    for (int kk = 0; kk < 16; ++kk) {
      float4 a = *(const float4*)&As[kk][ty*4];
      float4 b = *(const float4*)&Bs[kk][tx*4];
      acc[0][0]=fmaf(a.x,b.x,acc[0][0]); acc[0][1]=fmaf(a.x,b.y,acc[0][1]); acc[0][2]=fmaf(a.x,b.z,acc[0][2]); acc[0][3]=fmaf(a.x,b.w,acc[0][3]);
      acc[1][0]=fmaf(a.y,b.x,acc[1][0]); acc[1][1]=fmaf(a.y,b.y,acc[1][1]); acc[1][2]=fmaf(a.y,b.z,acc[1][2]); acc[1][3]=fmaf(a.y,b.w,acc[1][3]);
      acc[2][0]=fmaf(a.z,b.x,acc[2][0]); acc[2][1]=fmaf(a.z,b.y,acc[2][1]); acc[2][2]=fmaf(a.z,b.z,acc[2][2]); acc[2][3]=fmaf(a.z,b.w,acc[2][3]);
      acc[3][0]=fmaf(a.w,b.x,acc[3][0]); acc[3][1]=fmaf(a.w,b.y,acc[3][1]); acc[3][2]=fmaf(a.w,b.z,acc[3][2]); acc[3][3]=fmaf(a.w,b.w,acc[3][3]);
    }
  }
  {
#pragma clang fp contract(off)
    const int nb = n0 + tx * 4;
#pragma unroll
    for (int i = 0; i < 4; ++i) {
      float sz = szz[m0 + ty*4 + i];
      unsigned long long kb[4];
#pragma unroll
      for (int j = 0; j < 4; ++j) {
        float g2 = 2.0f * acc[i][j];     // exact (pow2 scale)
        float t1 = sz - g2;              // np: (szz - 2G)
        float d  = t1 + cbsq[nb + j];    // np: ... + scb
        kb[j] = key32(d, nb + j);
      }
      unsigned long long ka = kb[0] < kb[1] ? kb[0] : kb[1];
      unsigned long long kc = kb[2] < kb[3] ? kb[2] : kb[3];
      Ks[ty*4 + i][tx] = ka < kc ? ka : kc;
    }
  }
  __syncthreads();
  if (tid < 64) {
    unsigned long long best = Ks[tid][0];
#pragma unroll
    for (int t = 1; t < 16; ++t) {
      unsigned long long v = Ks[tid][t];
      best = v < best ? v : best;
    }
    atomicMin(&rowkeys[m0 + tid], best);
  }
}

// ---------------- elementwise / reduction kernels (np-f32 faithful) ---------
__global__ __launch_bounds__(256) void pw256_rows_kernel(const float* __restrict__ src,
                                                         float* __restrict__ dst,
                                                         int square) {
  int r = blockIdx.x * 256 + threadIdx.x;
  dst[r] = pw256sq(src + (size_t)r * 256, square != 0);
}

__global__ __launch_bounds__(256) void smean_kernel(const float* __restrict__ sf,
                                                    float* __restrict__ sm) {
#pragma clang fp contract(off)
  int i = blockIdx.x * 256 + threadIdx.x;     // B*C threads
  const float* a = sf + (size_t)i * 49;
  float r0=a[0],r1=a[1],r2=a[2],r3=a[3],r4=a[4],r5=a[5],r6=a[6],r7=a[7];
  for (int k = 8; k < 48; k += 8) {
    r0+=a[k+0]; r1+=a[k+1]; r2+=a[k+2]; r3+=a[k+3];
    r4+=a[k+4]; r5+=a[k+5]; r6+=a[k+6]; r7+=a[k+7];
  }
  float res = ((r0+r1)+(r2+r3))+((r4+r5)+(r6+r7));
  res += a[48];
  sm[i] = res / 49.0f;
}

__global__ __launch_bounds__(256) void previnit_kernel(const float* __restrict__ bos,
                                                       float* __restrict__ prev) {
  int i = blockIdx.x * 256 + threadIdx.x;
  prev[i] = bos[i & (DDIM - 1)];
}

__global__ __launch_bounds__(256) void gru_kernel(const float* __restrict__ gx,
                                                  const float* __restrict__ gh,
                                                  float* __restrict__ h) {
#pragma clang fp contract(off)
  int i = blockIdx.x * 256 + threadIdx.x;
  int b = i >> 9, j = i & 511;
  size_t o = (size_t)b * G3;
  float xr = gx[o + j], xz = gx[o + 512 + j], xn = gx[o + 1024 + j];
  float hr = gh[o + j], hz = gh[o + 512 + j], hn = gh[o + 1024 + j];
  float ar = xr + hr;
  float az = xz + hz;
  float er = expf(-ar);
  float ez = expf(-az);
  float r  = 1.0f / (1.0f + er);
  float zz = 1.0f / (1.0f + ez);
  float rh = r * hn;
  float an = xn + rh;
  float n  = tanhf(an);
  float hold = h[i];
  float t1 = (1.0f - zz) * n;
  float t2 = zz * hold;
  h[i] = t1 + t2;
}

__global__ __launch_bounds__(256) void film_kernel(const float* __restrict__ gb,
                                                   const float* __restrict__ sm,
                                                   const float* __restrict__ h,
                                                   float* __restrict__ pin) {
#pragma clang fp contract(off)
  int i = blockIdx.x * 256 + threadIdx.x;
  int b = i >> 9, j = i & 511;
  float gamma = gb[(size_t)b * 1024 + j];
  float beta  = gb[(size_t)b * 1024 + 512 + j];
  float t1 = 1.0f + gamma;
  float t2 = t1 * sm[i];
  float cval = t2 + beta;
  pin[(size_t)b * 1024 + j] = h[i];
  pin[(size_t)b * 1024 + 512 + j] = cval;
}

__global__ __launch_bounds__(256) void vq_apply_kernel(
    const unsigned long long* __restrict__ rowkeys,
    const float* __restrict__ cb, const float* __restrict__ zbuf,
    float* __restrict__ prev, int* __restrict__ idxarr,
    float* __restrict__ loss_acc, float* __restrict__ out, int t)
{
#pragma clang fp contract(off)
  int b = blockIdx.x, d = threadIdx.x;
  int idx = (int)(rowkeys[b] & 0xFFFFFFFFull);
  float zq = cb[(size_t)idx * DDIM + d];
  float zb = zbuf[(size_t)b * DDIM + d];
  float delta = zq - zb;
  float zste = zb + delta;                  // z + (z_q - z)
  size_t td = ((size_t)b * TSTEPS + t) * DDIM + d;
  out[OUT_CODES + td] = zste;
  out[OUT_ZC + td] = zb;
  prev[(size_t)b * DDIM + d] = zste;
  if (d == 0) {
    idxarr[b] = idx;
    out[OUT_IDX + (size_t)b * TSTEPS + t] = (float)idx;
  }
  float diff = zb - zq;
  __shared__ float red[256];
  red[d] = diff * diff; __syncthreads();
  for (int s = 128; s > 0; s >>= 1) { if (d < s) red[d] += red[d + s]; __syncthreads(); }
  if (d == 0) atomicAdd(loss_acc, red[0]);
}

// ---- CSR bucket build: rank within equal idx (ascending b == np.add.at order)
__global__ __launch_bounds__(1024) void csr_build_kernel(const int* __restrict__ idxarr,
                                                         int* __restrict__ list,
                                                         int* __restrict__ base,
                                                         int* __restrict__ cnts) {
  __shared__ int sidx[BATCH];
  __shared__ int scnt[KCB];       // 32 KB
  __shared__ int spart[1024];
  const int t = threadIdx.x;
  sidx[t] = idxarr[t];
  for (int i = t; i < KCB; i += 1024) scnt[i] = 0;
  __syncthreads();
  const int my = sidx[t];
  atomicAdd(&scnt[my], 1);
  int rank = 0;
  for (int b = 0; b < t; ++b) rank += (sidx[b] == my) ? 1 : 0;
  __syncthreads();
  const int c0 = t * 8;
  int loc[8]; int s0 = 0;
#pragma unroll
  for (int i = 0; i < 8; ++i) { loc[i] = s0; s0 += scnt[c0 + i]; }
  spart[t] = s0;
  __syncthreads();
  if (t == 0) {
    int run = 0;
    for (int i = 0; i < 1024; ++i) { int v = spart[i]; spart[i] = run; run += v; }
  }
  __syncthreads();
  const int off = spart[t];
#pragma unroll
  for (int i = 0; i < 8; ++i) { base[c0 + i] = off + loc[i]; cnts[c0 + i] = scnt[c0 + i]; }
  const int kb = my >> 3, kr = my & 7;
  int bb = spart[kb];
  for (int i = 0; i < kr; ++i) bb += scnt[(kb << 3) + i];
  list[bb + rank] = t;
}

// ---- cs chain fused: cs = 0.99cs+0.01cnt; ntot = np-pairwise(cs); smooth ----
__global__ __launch_bounds__(256) void cs_fused_kernel(float* __restrict__ cs,
                                                       const int* __restrict__ cnts,
                                                       float* __restrict__ nt) {
#pragma clang fp contract(off)
  __shared__ float scs[KCB];      // 32 KB
  __shared__ float s64v[64];
  const int t = threadIdx.x;
  for (int i = t; i < KCB; i += 256) {
    float a = 0.99f * cs[i];
    float b = 0.01f * (float)cnts[i];
    scs[i] = a + b;
  }
  __syncthreads();
  if (t < 64) s64v[t] = pw128(scs + t * 128);
  __syncthreads();
  if (t == 0) {
    float v[64];
    for (int i = 0; i < 64; ++i) v[i] = s64v[i];
    for (int len = 64; len > 1; len >>= 1)
      for (int i = 0; i < (len >> 1); ++i) v[i] = v[2*i] + v[2*i+1];
    nt[0] = v[0];
    s64v[0] = v[0];
  }
  __syncthreads();
  const float n = s64v[0];
  const float den = n + 0.08192f;          // f32(K*EPS)
  for (int i = t; i < KCB; i += 256) {
    float t1 = scs[i] + 1e-5f;
    float q = t1 / den;
    cs[i] = q * n;
  }
}

// ---- EMA fused v4: 8 rows/block; gather with 16-deep load batching ---------
// f32 adds stay in ascending-b order (np.add.at); only LOADS are batched.
// cbsq tail: 16 threads compute numpy pw128's 16 accumulator chains (exact
// numpy order), thread 0 does the exact tree combine.
__global__ __launch_bounds__(256) void ema_fused_kernel(
    float* __restrict__ ew, const int* __restrict__ list,
    const int* __restrict__ base, const int* __restrict__ cnts,
    const float* __restrict__ zbuf, const float* __restrict__ cs,
    float* __restrict__ cb, float* __restrict__ cbsq)
{
#pragma clang fp contract(off)
  __shared__ float row2[256];
  __shared__ float ch[16];
  const int d = threadIdx.x;
  for (int r = 0; r < 8; ++r) {
    const int k = blockIdx.x * 8 + r;
    const int start = base[k], cnt = cnts[k];
    float acc = 0.0f;
    int i = 0;
    for (; i + 16 <= cnt; i += 16) {
      int bi[16];
#pragma unroll
      for (int u = 0; u < 16; ++u) bi[u] = list[start + i + u];
      float v[16];
#pragma unroll
      for (int u = 0; u < 16; ++u) v[u] = zbuf[(size_t)bi[u] * DDIM + d];
#pragma unroll
      for (int u = 0; u < 16; ++u) acc += v[u];   // exact ascending-b order
    }
    for (; i < cnt; ++i) {
      acc += zbuf[(size_t)list[start + i] * DDIM + d];
    }
    const size_t o = (size_t)k * DDIM + d;
    float a = 0.99f * ew[o];
    float bb = 0.01f * acc;
    float e = a + bb;
    ew[o] = e;
    float c = e / cs[k];
    cb[o] = c;
    row2[d] = c * c;
    __syncthreads();
    if (d < 16) {
      int h = d >> 3, j = d & 7;
      const float* p = row2 + h * 128 + j;
      float rr = p[0];
      for (int i2 = 1; i2 < 16; ++i2) rr += p[8 * i2];
      ch[d] = rr;
    }
    __syncthreads();
    if (d == 0) {
      float s0 = ((ch[0]+ch[1])+(ch[2]+ch[3]))+((ch[4]+ch[5])+(ch[6]+ch[7]));
      float s1 = ((ch[8]+ch[9])+(ch[10]+ch[11]))+((ch[12]+ch[13])+(ch[14]+ch[15]));
      cbsq[k] = s0 + s1;
    }
    __syncthreads();
  }
}

__global__ __launch_bounds__(256) void hfinal_kernel(const float* __restrict__ h,
                                                     float* __restrict__ out) {
  int i = blockIdx.x * 256 + threadIdx.x;
  out[OUT_HF + i] = h[i];
}

__global__ void loss_kernel(const float* __restrict__ loss_acc,
                            float* __restrict__ out) {
  out[OUT_LOSS] = 0.25f * (*loss_acc) / ((float)(BATCH * DDIM)) / (float)TSTEPS;
}

// ---------------- launch ----------------
extern "C" void kernel_launch(void* const* d_in, const int* in_sizes, int n_in,
                              void* d_out, int out_size, void* d_ws, size_t ws_size,
                              hipStream_t stream) {
  const float* sf    = (const float*)d_in[0];
  const float* bos   = (const float*)d_in[1];
  const float* W_ih  = (const float*)d_in[2];
  const float* W_hh  = (const float*)d_in[3];
  const float* b_ih  = (const float*)d_in[4];
  const float* b_hh  = (const float*)d_in[5];
  const float* Wg    = (const float*)d_in[6];
  const float* bg    = (const float*)d_in[7];
  const float* Wb    = (const float*)d_in[8];
  const float* bb    = (const float*)d_in[9];
  const float* W1    = (const float*)d_in[10];
  const float* b1    = (const float*)d_in[11];
  const float* W2    = (const float*)d_in[12];
  const float* b2    = (const float*)d_in[13];
  const float* cb_in = (const float*)d_in[14];
  const float* cs_in = (const float*)d_in[15];
  const float* ew_in = (const float*)d_in[16];

  float* ws  = (float*)d_ws;
  float* out = (float*)d_out;

  float* CB   = ws + WS_CB;
  float* EW   = ws + WS_EW;
  int*   LIST = (int*)(ws + WS_CSR);
  int*   BASE = LIST + BATCH;
  int*   CNTS = BASE + KCB;
  float* SM   = ws + WS_SM;
  float* H    = ws + WS_H;
  float* PREV = ws + WS_PREV;
  float* Z    = ws + WS_Z;
  float* GX   = ws + WS_GX;
  float* GH   = ws + WS_GH;
  float* GB   = ws + WS_GB;
  float* PIN  = ws + WS_PIN;
  float* H1   = ws + WS_H1;
  float* CS   = ws + WS_CS;
  float* CBSQ = ws + WS_CBSQ;
  float* SZZ  = ws + WS_SZZ;
  float* NT   = ws + WS_NT;
  float* LOSS = ws + WS_LOSS;
  int*   IDX  = (int*)(ws + WS_IDX);
  unsigned long long* ROWK = (unsigned long long*)(ws + WS_ROWK);
  float* WGWB = ws + WS_WGWB;
  float* BGBB = ws + WS_BGBB;

  // ---- per-launch init ----
  (void)hipMemcpyAsync(CB, cb_in, (size_t)KCB * DDIM * 4, hipMemcpyDeviceToDevice, stream);
  (void)hipMemcpyAsync(EW, ew_in, (size_t)KCB * DDIM * 4, hipMemcpyDeviceToDevice, stream);
  (void)hipMemcpyAsync(CS, cs_in, (size_t)KCB * 4, hipMemcpyDeviceToDevice, stream);
  (void)hipMemcpyAsync(WGWB, Wg, (size_t)CDIM * HD * 4, hipMemcpyDeviceToDevice, stream);
  (void)hipMemcpyAsync(WGWB + (size_t)CDIM * HD, Wb, (size_t)CDIM * HD * 4, hipMemcpyDeviceToDevice, stream);
  (void)hipMemcpyAsync(BGBB, bg, CDIM * 4, hipMemcpyDeviceToDevice, stream);
  (void)hipMemcpyAsync(BGBB + CDIM, bb, CDIM * 4, hipMemcpyDeviceToDevice, stream);
  (void)hipMemsetAsync(H, 0, (size_t)BATCH * HD * 4, stream);
  (void)hipMemsetAsync(LOSS, 0, 8, stream);
  previnit_kernel<<<BATCH * DDIM / 256, 256, 0, stream>>>(bos, PREV);
  smean_kernel<<<BATCH * CDIM / 256, 256, 0, stream>>>(sf, SM);
  pw256_rows_kernel<<<KCB / 256, 256, 0, stream>>>(CB, CBSQ, 1);

  for (int t = 0; t < TSTEPS; ++t) {
    (void)hipMemsetAsync(ROWK, 0xFF, BATCH * 8, stream);

    // GRU gates
    gemm_nt<false><<<dim3(16, G3/64), 256, 0, stream>>>(PREV, DDIM, W_ih, DDIM, GX, G3, b_ih, DDIM);
    gemm_nt<false><<<dim3(16, G3/64), 256, 0, stream>>>(H, HD, W_hh, HD, GH, G3, b_hh, HD);
    gru_kernel<<<BATCH * HD / 256, 256, 0, stream>>>(GX, GH, H);

    // FiLM + pin
    gemm_nt<false><<<dim3(16, 1024/64), 256, 0, stream>>>(H, HD, WGWB, HD, GB, 1024, BGBB, HD);
    film_kernel<<<BATCH * CDIM / 256, 256, 0, stream>>>(GB, SM, H, PIN);

    // MLP
    gemm_nt<true ><<<dim3(16, HD/64), 256, 0, stream>>>(PIN, 1024, W1, 1024, H1, HD, b1, 1024);
    gemm_nt<false><<<dim3(16, DDIM/64), 256, 0, stream>>>(H1, HD, W2, HD, Z, DDIM, b2, HD);

    // VQ
    pw256_rows_kernel<<<BATCH / 256, 256, 0, stream>>>(Z, SZZ, 1);
    gemm_score_argmin<<<dim3(16, KCB/64), 256, 0, stream>>>(Z, CB, CBSQ, SZZ, ROWK);
    vq_apply_kernel<<<BATCH, 256, 0, stream>>>(ROWK, CB, Z, PREV, IDX, LOSS, out, t);

    // EMA via CSR (deterministic np.add.at order)
    csr_build_kernel<<<1, 1024, 0, stream>>>(IDX, LIST, BASE, CNTS);
    cs_fused_kernel<<<1, 256, 0, stream>>>(CS, CNTS, NT);
    ema_fused_kernel<<<KCB/8, 256, 0, stream>>>(EW, LIST, BASE, CNTS, Z, CS, CB, CBSQ);
  }

  hfinal_kernel<<<BATCH * HD / 256, 256, 0, stream>>>(H, out);
  loss_kernel<<<1, 1, 0, stream>>>(LOSS, out);
}